// Round 11
// baseline (556.187 us; speedup 1.0000x reference)
//
#include <hip/hip_runtime.h>
#include <hip/hip_bf16.h>
#include <math.h>

#define NVERT 150000
#define NFACE 300000
#define LVOL  192
#define TVB   32
#define MTV   48      // vertices per block in mlp kernel (M = 3 MFMA rows)

// mega_prep2 block-range partition: gather prerequisites only
#define P2_POOL1 3456
#define P2_POOL2 432
#define P2_WC    193
#define P2_CP0   3456
#define P2_POOL2_START (P2_POOL1)
#define P2_WC_START    (P2_POOL1 + P2_POOL2)
#define P2_CP0_START   (P2_POOL1 + P2_POOL2 + P2_WC)

// extra blocks appended to gather grid (mlp-only prerequisites)
#define NB_NORM 1172
#define NB_TRS  1024

#define NBUCKET 13824     // 24^3 cells of 8^3 voxels
#define WS_BIG_NEED  44808576ull
#define WS_B16_NEED  58964352ull   // + 14,155,776 B for vol0b (192^3 bf16)
#define WS_SORT_NEED 60219648ull   // + hist(55,296) + keys(600,000) + perm(600,000)

typedef short v8s __attribute__((ext_vector_type(8)));
typedef float v4f __attribute__((ext_vector_type(4)));

__device__ __forceinline__ float s2f(short s) {
    unsigned int u = ((unsigned int)(unsigned short)s) << 16;
    return __builtin_bit_cast(float, u);
}
__device__ __forceinline__ short f2s(float f) {
    __hip_bfloat16 h = __float2bfloat16(f);
    return __builtin_bit_cast(short, h);
}
__device__ __forceinline__ float lrelu(float x) { return x > 0.f ? x : 0.15f * x; }

__device__ __forceinline__ float ldf(const void* __restrict__ p, int i, int bf) {
    return bf ? s2f(((const short*)p)[i]) : ((const float*)p)[i];
}

// Banked H addressing (shorts): col c in [0,512), row r in [0,48).
__device__ __forceinline__ int haddr(int r, int c) {
    int hi  = c >> 7;
    int mid = (c >> 4) & 7;
    int lo  = c & 15;
    int wc  = hi * 64 + (mid & 3) * 16 + lo;
    return ((mid < 4) ? 0 : 12672) + r * 264 + wc;
}

// ---- detect input dtype (bf16 vs fp32) ----
__global__ void detect_kernel(const void* __restrict__ v, int* __restrict__ flag) {
    __shared__ int s_ok;
    int t = threadIdx.x;
    if (t == 0) s_ok = 1;
    __syncthreads();
    float x = s2f(((const short*)v)[t]);
    if (!(fabsf(x) <= 1.0f)) atomicAnd(&s_ok, 0);
    __syncthreads();
    if (t == 0) *flag = s_ok;
}

// ---- spatial counting sort (3 kernels): bucket verts into 8^3-voxel cells ----
// R10 PMC: sorted gather FETCH 246.8 -> 62 MB. xloc is written in SLOT order
// (coalesced 256B rows); mlp consumes slots and indirects only v/n_accum/out
// through perm (small L2-resident arrays) — avoids R10's 130 MB scattered-write
// amplification on xloc.
__global__ __launch_bounds__(256) void sort_hist_kernel(
    const void* __restrict__ v, int* __restrict__ hist, int* __restrict__ keys,
    const int* __restrict__ flag)
{
    const int bf = *flag;
    int vert = blockIdx.x * 256 + threadIdx.x;
    if (vert >= NVERT) return;
    float vx = ldf(v, vert * 3 + 0, bf);
    float vy = ldf(v, vert * 3 + 1, bf);
    float vz = ldf(v, vert * 3 + 2, bf);
    int cx = min(max((int)rintf((vx + 1.0f) * 96.0f), 2), 189);
    int cy = min(max((int)rintf((vy + 1.0f) * 96.0f), 2), 189);
    int cz = min(max((int)rintf((vz + 1.0f) * 96.0f), 2), 189);
    int key = ((cx >> 3) * 24 + (cy >> 3)) * 24 + (cz >> 3);
    keys[vert] = key;
    atomicAdd(&hist[key], 1);
}

// one block, 1024 threads: in-place exclusive scan of hist[NBUCKET]
__global__ __launch_bounds__(1024) void sort_scan_kernel(int* __restrict__ hist)
{
    __shared__ int partial[1024];
    const int t = threadIdx.x;
    const int CH = 14;                       // 1024*14 = 14336 >= 13824
    int base = t * CH;
    int sum = 0;
    #pragma unroll
    for (int i = 0; i < CH; i++) {
        int idx = base + i;
        if (idx < NBUCKET) sum += hist[idx];
    }
    partial[t] = sum;
    __syncthreads();
    // Hillis-Steele inclusive scan
    for (int off = 1; off < 1024; off <<= 1) {
        int x = (t >= off) ? partial[t - off] : 0;
        __syncthreads();
        partial[t] += x;
        __syncthreads();
    }
    int run = partial[t] - sum;              // exclusive base for this chunk
    for (int i = 0; i < CH; i++) {
        int idx = base + i;
        if (idx < NBUCKET) {
            int c = hist[idx];
            hist[idx] = run;                 // hist becomes cursor (exclusive offsets)
            run += c;
        }
    }
}

__global__ __launch_bounds__(256) void sort_scatter_kernel(
    int* __restrict__ cursor, const int* __restrict__ keys, int* __restrict__ perm)
{
    int vert = blockIdx.x * 256 + threadIdx.x;
    if (vert >= NVERT) return;
    int pos = atomicAdd(&cursor[keys[vert]], 1);
    perm[pos] = vert;
}

// ---------------- mega_prep2: pools | Wcomb | [vol0b] — gather prerequisites only ----
__global__ __launch_bounds__(256) void mega_prep2_kernel(
    const void* __restrict__ volume,
    short* __restrict__ vol1b, short* __restrict__ vol2b,
    const void* __restrict__ conv_w, const void* __restrict__ lfc_w,
    const void* __restrict__ conv_b, const void* __restrict__ lfc_b,
    short* __restrict__ Wcomb, float* __restrict__ bcomb,
    const int* __restrict__ flag,
    short* __restrict__ vol0b)
{
    const int bf = *flag;
    const int bid = blockIdx.x;
    const int t = threadIdx.x;

    if (bid < P2_POOL1) {
        int id = bid * 256 + t;
        int z = id % 96, y = (id / 96) % 96, x = id / (96 * 96);
        float s = 0.f;
        #pragma unroll
        for (int a = 0; a < 2; a++)
            #pragma unroll
            for (int b = 0; b < 2; b++)
                #pragma unroll
                for (int c = 0; c < 2; c++)
                    s += ldf(volume, (2 * x + a) * (LVOL * LVOL) + (2 * y + b) * LVOL + (2 * z + c), bf);
        s *= 0.125f;
        vol1b[id] = f2s(s);
    } else if (bid < P2_WC_START) {
        int id = (bid - P2_POOL2_START) * 256 + t;
        int z = id % 48, y = (id / 48) % 48, x = id / (48 * 48);
        float s = 0.f;
        for (int a = 0; a < 4; a++)
            for (int b = 0; b < 4; b++)
                #pragma unroll
                for (int c = 0; c < 4; c++)
                    s += ldf(volume, (4 * x + a) * (LVOL * LVOL) + (4 * y + b) * LVOL + (4 * z + c), bf);
        s *= 0.015625f;
        vol2b[id] = f2s(s);
    } else if (bid < P2_CP0_START) {
        int id = (bid - P2_WC_START) * 256 + t;
        if (id < 49152) {
            int j = id / 384, k = id - j * 384;
            float acc = 0.f;
            if (k < 375) {
                float a0 = 0.f, a1 = 0.f, a2 = 0.f, a3 = 0.f;
                for (int o = 0; o < 128; o += 4) {
                    a0 += ldf(conv_w, (o + 0) * 375 + k, bf) * ldf(lfc_w, (o + 0) * 128 + j, bf);
                    a1 += ldf(conv_w, (o + 1) * 375 + k, bf) * ldf(lfc_w, (o + 1) * 128 + j, bf);
                    a2 += ldf(conv_w, (o + 2) * 375 + k, bf) * ldf(lfc_w, (o + 2) * 128 + j, bf);
                    a3 += ldf(conv_w, (o + 3) * 375 + k, bf) * ldf(lfc_w, (o + 3) * 128 + j, bf);
                }
                acc = (a0 + a1) + (a2 + a3);
            }
            int tile = j >> 4, ln = j & 15;
            int kk = k >> 5, r = k & 31, qq = r >> 3, e = r & 7;
            Wcomb[((tile * 12 + kk) * 64 + qq * 16 + ln) * 8 + e] = f2s(acc);
        } else if (id < 49152 + 128) {
            int j = id - 49152;
            float acc = ldf(lfc_b, j, bf);
            for (int o = 0; o < 128; o++) acc += ldf(conv_b, o, bf) * ldf(lfc_w, o * 128 + j, bf);
            bcomb[j] = acc;
        }
    } else {
        if (bf) return;                 // bf16 input: gather reads volume directly
        int id = (bid - P2_CP0_START) * 2048 + t * 8;
        const float* vp = (const float*)volume;
        short tmp[8];
        #pragma unroll
        for (int i = 0; i < 8; i++) tmp[i] = f2s(vp[id + i]);
        *(v8s*)&vol0b[id] = *(v8s*)tmp;
    }
}

// ================= gather_ext: gather+conv (perm order) | normals | transposes ====
// xloc is written in SLOT order (coalesced); mlp maps slot->vert via perm.
__global__ __launch_bounds__(256, 6) void gather_ext_kernel(
    const void* __restrict__ v,
    const int* __restrict__ f, float* __restrict__ n_accum,
    const void* __restrict__ volume,
    const short* __restrict__ vol1b,
    const short* __restrict__ vol2b,
    const short* __restrict__ vol0b,     // may be null (fp32 input, small ws)
    const int* __restrict__ perm,        // may be null (identity order)
    const short* __restrict__ Wcomb,
    const float* __restrict__ bcomb,
    const void* __restrict__ fc2_w, const void* __restrict__ fc3_w,
    short* __restrict__ fc2T, short* __restrict__ fc3T,
    short* __restrict__ xloc,
    const int* __restrict__ flag, int ngather)
{
    __shared__ __align__(16) short sCube[TVB * 392];
    __shared__ int sIdx[TVB * 4];

    const int bf = *flag;
    const int t = threadIdx.x;
    const int bid = blockIdx.x;

    if (bid >= ngather) {
        int rb = bid - ngather;
        if (rb < NB_NORM) {
            int ft = rb * 256 + t;
            if (ft >= NFACE) return;
            int i0 = f[ft * 3 + 0], i1 = f[ft * 3 + 1], i2 = f[ft * 3 + 2];
            float p0x = ldf(v, i0 * 3 + 0, bf), p0y = ldf(v, i0 * 3 + 1, bf), p0z = ldf(v, i0 * 3 + 2, bf);
            float p1x = ldf(v, i1 * 3 + 0, bf), p1y = ldf(v, i1 * 3 + 1, bf), p1z = ldf(v, i1 * 3 + 2, bf);
            float p2x = ldf(v, i2 * 3 + 0, bf), p2y = ldf(v, i2 * 3 + 1, bf), p2z = ldf(v, i2 * 3 + 2, bf);
            float e1x = p1x - p0x, e1y = p1y - p0y, e1z = p1z - p0z;
            float e2x = p2x - p0x, e2y = p2y - p0y, e2z = p2z - p0z;
            float cx = e1y * e2z - e1z * e2y;
            float cy = e1z * e2x - e1x * e2z;
            float cz = e1x * e2y - e1y * e2x;
            atomicAdd(&n_accum[i0 * 3 + 0], cx); atomicAdd(&n_accum[i0 * 3 + 1], cy); atomicAdd(&n_accum[i0 * 3 + 2], cz);
            atomicAdd(&n_accum[i1 * 3 + 0], cx); atomicAdd(&n_accum[i1 * 3 + 1], cy); atomicAdd(&n_accum[i1 * 3 + 2], cz);
            atomicAdd(&n_accum[i2 * 3 + 0], cx); atomicAdd(&n_accum[i2 * 3 + 1], cy); atomicAdd(&n_accum[i2 * 3 + 2], cz);
        } else {
            int id = (rb - NB_NORM) * 256 + t;
            if (id < 131072) {
                int col = id >> 8, k = id & 255;
                int tile = col >> 4, ln = col & 15;
                int kk = k >> 5, r = k & 31, qq = r >> 3, e = r & 7;
                fc2T[((tile * 8 + kk) * 64 + qq * 16 + ln) * 8 + e] = f2s(ldf(fc2_w, k * 512 + col, bf));
            } else {
                int i = id - 131072;
                int col = i >> 9, k = i & 511;
                int tile = col >> 4, ln = col & 15;
                int kk = k >> 5, r = k & 31, qq = r >> 3, e = r & 7;
                fc3T[((tile * 16 + kk) * 64 + qq * 16 + ln) * 8 + e] = f2s(ldf(fc3_w, k * 256 + col, bf));
            }
        }
        return;
    }

    const int base = bid * TVB;
    const int w = t >> 6, L = t & 63, q = L >> 4, ln = L & 15;
    const short* v0 = bf ? (const short*)volume : vol0b;   // null => fp32 fallback

    if (t < TVB) {
        int slot = min(base + t, NVERT - 1);
        int vert = perm ? perm[slot] : slot;
        float vx = ldf(v, vert * 3 + 0, bf);
        float vy = ldf(v, vert * 3 + 1, bf);
        float vz = ldf(v, vert * 3 + 2, bf);
        #pragma unroll
        for (int n = 0; n < 3; n++) {
            float scl = (n == 0) ? 96.0f : (n == 1 ? 48.0f : 24.0f);
            int dim = LVOL >> n, lim = dim - 3;
            int cx = min(max((int)rintf((vx + 1.0f) * scl), 2), lim);
            int cy = min(max((int)rintf((vy + 1.0f) * scl), 2), lim);
            int cz = min(max((int)rintf((vz + 1.0f) * scl), 2), lim);
            sIdx[t * 4 + n] = (cx * dim + cy) * dim + (cz - 2);
        }
    }
    __syncthreads();

    for (int idx = t; idx < TVB * 75; idx += 256) {
        int n   = idx / 800;
        int rem = idx - n * 800;
        int vl  = rem / 25;
        int dd  = rem - vl * 25;
        int di  = dd / 5, dj = dd - di * 5;
        int dim = LVOL >> n;
        int addr = sIdx[vl * 4 + n] + (di - 2) * dim * dim + (dj - 2) * dim;
        short* dst = &sCube[vl * 392 + n * 125 + dd * 5];
        if (n == 0 && v0 == nullptr) {
            const float* vp = (const float*)volume;
            #pragma unroll
            for (int i = 0; i < 5; i++) dst[i] = f2s(vp[addr + i]);
        } else {
            const short* lvl = (n == 0) ? v0 : (n == 1 ? vol1b : vol2b);
            #pragma unroll
            for (int i = 0; i < 5; i++) dst[i] = lvl[addr + i];
        }
    }
    for (int idx = t; idx < TVB * 9; idx += 256) {
        int vl = idx / 9, rr = idx - vl * 9;
        sCube[vl * 392 + 375 + rr] = 0;
    }
    __syncthreads();

    #pragma unroll
    for (int nt = 0; nt < 2; nt++) {
        int col = w * 32 + nt * 16 + ln;
        const short* wb = Wcomb + ((w * 2 + nt) * 12 * 64 + q * 16 + ln) * 8;
        v4f acc0 = {0.f, 0.f, 0.f, 0.f}, acc1 = {0.f, 0.f, 0.f, 0.f};
        #pragma unroll
        for (int k0 = 0; k0 < 12; k0++) {
            v8s b  = *(const v8s*)(wb + k0 * 512);
            v8s a0 = *(const v8s*)&sCube[ln * 392 + k0 * 32 + q * 8];
            v8s a1 = *(const v8s*)&sCube[(16 + ln) * 392 + k0 * 32 + q * 8];
            acc0 = __builtin_amdgcn_mfma_f32_16x16x32_bf16(a0, b, acc0, 0, 0, 0);
            acc1 = __builtin_amdgcn_mfma_f32_16x16x32_bf16(a1, b, acc1, 0, 0, 0);
        }
        float bias = bcomb[col];
        #pragma unroll
        for (int r = 0; r < 4; r++) {
            xloc[(base + q * 4 + r) * 128 + col]      = f2s(acc0[r] + bias);
            xloc[(base + 16 + q * 4 + r) * 128 + col] = f2s(acc1[r] + bias);
        }
    }
}

// ---- kernel B: MLP, 48 slots/block (M=3 MFMA rows) ----
// Processes SLOTS in sorted order: xloc read is linear (coalesced); only the
// small arrays (v, n_accum, out — 1.8 MB each, L2-resident) are indirected
// through perm. Structure otherwise unchanged from R7 control.
__global__ __launch_bounds__(256, 3) void mlp_kernel(
    const void* __restrict__ v,
    const float* __restrict__ n_accum,
    const short* __restrict__ xloc,
    const int* __restrict__ perm,        // may be null (identity)
    const short* __restrict__ fc2T,
    const short* __restrict__ fc3T,
    const void* __restrict__ fc1_w, const void* __restrict__ fc1_b,
    const void* __restrict__ fc2_b, const void* __restrict__ fc3_b,
    const void* __restrict__ fc4_w, const void* __restrict__ fc4_b,
    void* __restrict__ out,
    const int* __restrict__ flag)
{
    __shared__ __align__(16) char smem[52224];
    short* sX  = (short*)smem;                 // [48][264] phase 0-1 (25,344 B)
    short* sHB = (short*)smem;                 // banked H base (L at +0, U at +12672 shorts)
    short* s3  = (short*)smem;                 // [48][264] phase 4-5 - aliases L bank
    short* sW4 = (short*)(smem + 50688);       // [3][256]  persistent (1,536 B)

    const int bf = *flag;
    const int t = threadIdx.x;
    const int base = blockIdx.x * MTV;         // grid is exact: 150000 = 48 * 3125
    const int w = t >> 6, L = t & 63, q = L >> 4, ln = L & 15;
    const int laneoff = (q * 16 + ln) * 8;     // fragment-major lane offset (shorts)

    for (int id = t; id < MTV * 16; id += 256) {
        int row = id >> 4, seg = id & 15;
        v8s x = *(const v8s*)(xloc + (base + row) * 128 + seg * 8);
        *(v8s*)&sX[row * 264 + 128 + seg * 8] = x;
    }

    for (int i = t; i < 768; i += 256) {
        int j = i >> 8, k = i & 255;
        sW4[i] = f2s(ldf(fc4_w, k * 3 + j, bf));
    }

    {
        int vi = t >> 2, cb = (t & 3) * 32;
        if (vi < MTV) {
            int vert = perm ? perm[base + vi] : (base + vi);
            float i0 = ldf(v, vert * 3 + 0, bf);
            float i1 = ldf(v, vert * 3 + 1, bf);
            float i2 = ldf(v, vert * 3 + 2, bf);
            float nx = n_accum[vert * 3 + 0];
            float ny = n_accum[vert * 3 + 1];
            float nz = n_accum[vert * 3 + 2];
            float inv = 1.0f / fmaxf(sqrtf(nx * nx + ny * ny + nz * nz), 1e-12f);
            float i3 = nx * inv, i4 = ny * inv, i5 = nz * inv;
            #pragma unroll 8
            for (int i = 0; i < 32; i++) {
                int c = cb + i;
                float acc = ldf(fc1_b, c, bf)
                          + i0 * ldf(fc1_w, 0 * 128 + c, bf)
                          + i1 * ldf(fc1_w, 1 * 128 + c, bf)
                          + i2 * ldf(fc1_w, 2 * 128 + c, bf)
                          + i3 * ldf(fc1_w, 3 * 128 + c, bf)
                          + i4 * ldf(fc1_w, 4 * 128 + c, bf)
                          + i5 * ldf(fc1_w, 5 * 128 + c, bf);
                sX[vi * 264 + c] = f2s(lrelu(acc));
            }
        }
    }
    __syncthreads();

    {
        #pragma unroll
        for (int nt = 4; nt < 8; nt++) {
            int col = w * 128 + nt * 16 + ln;
            const short* bb = fc2T + (w * 8 + nt) * 8 * 512 + laneoff;
            v4f acc0 = {0.f, 0.f, 0.f, 0.f}, acc1 = {0.f, 0.f, 0.f, 0.f}, acc2 = {0.f, 0.f, 0.f, 0.f};
            #pragma unroll
            for (int k0 = 0; k0 < 8; k0++) {
                v8s b  = *(const v8s*)(bb + k0 * 512);
                v8s a0 = *(const v8s*)&sX[(ln) * 264 + k0 * 32 + q * 8];
                v8s a1 = *(const v8s*)&sX[(16 + ln) * 264 + k0 * 32 + q * 8];
                v8s a2 = *(const v8s*)&sX[(32 + ln) * 264 + k0 * 32 + q * 8];
                acc0 = __builtin_amdgcn_mfma_f32_16x16x32_bf16(a0, b, acc0, 0, 0, 0);
                acc1 = __builtin_amdgcn_mfma_f32_16x16x32_bf16(a1, b, acc1, 0, 0, 0);
                acc2 = __builtin_amdgcn_mfma_f32_16x16x32_bf16(a2, b, acc2, 0, 0, 0);
            }
            float bias = ldf(fc2_b, col, bf);
            int wc = 12672 + w * 64 + (nt - 4) * 16 + ln;   // U bank
            #pragma unroll
            for (int r = 0; r < 4; r++) {
                sHB[(q * 4 + r) * 264 + wc]      = f2s(lrelu(acc0[r] + bias));
                sHB[(16 + q * 4 + r) * 264 + wc] = f2s(lrelu(acc1[r] + bias));
                sHB[(32 + q * 4 + r) * 264 + wc] = f2s(lrelu(acc2[r] + bias));
            }
        }

        v4f accL[4][3];
        #pragma unroll
        for (int nt = 0; nt < 4; nt++)
            #pragma unroll
            for (int m = 0; m < 3; m++)
                accL[nt][m] = (v4f){0.f, 0.f, 0.f, 0.f};

        #pragma unroll
        for (int nt = 0; nt < 4; nt++) {
            const short* bb = fc2T + (w * 8 + nt) * 8 * 512 + laneoff;
            #pragma unroll
            for (int k0 = 0; k0 < 8; k0++) {
                v8s b  = *(const v8s*)(bb + k0 * 512);
                v8s a0 = *(const v8s*)&sX[(ln) * 264 + k0 * 32 + q * 8];
                v8s a1 = *(const v8s*)&sX[(16 + ln) * 264 + k0 * 32 + q * 8];
                v8s a2 = *(const v8s*)&sX[(32 + ln) * 264 + k0 * 32 + q * 8];
                accL[nt][0] = __builtin_amdgcn_mfma_f32_16x16x32_bf16(a0, b, accL[nt][0], 0, 0, 0);
                accL[nt][1] = __builtin_amdgcn_mfma_f32_16x16x32_bf16(a1, b, accL[nt][1], 0, 0, 0);
                accL[nt][2] = __builtin_amdgcn_mfma_f32_16x16x32_bf16(a2, b, accL[nt][2], 0, 0, 0);
            }
        }
        __syncthreads();   // all waves done READING sX; L bank region is dead

        #pragma unroll
        for (int nt = 0; nt < 4; nt++) {
            int col = w * 128 + nt * 16 + ln;
            float bias = ldf(fc2_b, col, bf);
            int wc = w * 64 + nt * 16 + ln;                 // L bank
            #pragma unroll
            for (int r = 0; r < 4; r++) {
                sHB[(q * 4 + r) * 264 + wc]      = f2s(lrelu(accL[nt][0][r] + bias));
                sHB[(16 + q * 4 + r) * 264 + wc] = f2s(lrelu(accL[nt][1][r] + bias));
                sHB[(32 + q * 4 + r) * 264 + wc] = f2s(lrelu(accL[nt][2][r] + bias));
            }
        }
    }
    __syncthreads();

    {
        v4f acc[4][3];
        #pragma unroll
        for (int nt = 0; nt < 4; nt++)
            #pragma unroll
            for (int m = 0; m < 3; m++)
                acc[nt][m] = (v4f){0.f, 0.f, 0.f, 0.f};

        #pragma unroll
        for (int half = 0; half < 2; half++) {
            v8s A0[8], A1[8], A2[8];
            #pragma unroll
            for (int k0 = 0; k0 < 8; k0++) {
                int c = half * 256 + k0 * 32 + q * 8;
                A0[k0] = *(const v8s*)&sHB[haddr(ln, c)];
                A1[k0] = *(const v8s*)&sHB[haddr(16 + ln, c)];
                A2[k0] = *(const v8s*)&sHB[haddr(32 + ln, c)];
            }
            #pragma unroll
            for (int nt = 0; nt < 4; nt++) {
                const short* bb = fc3T + ((w * 4 + nt) * 16 + half * 8) * 512 + laneoff;
                v8s B[8];
                #pragma unroll
                for (int k0 = 0; k0 < 8; k0++) B[k0] = *(const v8s*)(bb + k0 * 512);
                #pragma unroll
                for (int k0 = 0; k0 < 8; k0++) {
                    acc[nt][0] = __builtin_amdgcn_mfma_f32_16x16x32_bf16(A0[k0], B[k0], acc[nt][0], 0, 0, 0);
                    acc[nt][1] = __builtin_amdgcn_mfma_f32_16x16x32_bf16(A1[k0], B[k0], acc[nt][1], 0, 0, 0);
                    acc[nt][2] = __builtin_amdgcn_mfma_f32_16x16x32_bf16(A2[k0], B[k0], acc[nt][2], 0, 0, 0);
                }
            }
        }
        __syncthreads();   // all waves done READING H; safe to overwrite with s3

        #pragma unroll
        for (int nt = 0; nt < 4; nt++) {
            int col = w * 64 + nt * 16 + ln;
            float bias = ldf(fc3_b, col, bf);
            #pragma unroll
            for (int r = 0; r < 4; r++) {
                s3[(q * 4 + r) * 264 + col]      = f2s(lrelu(acc[nt][0][r] + bias));
                s3[(16 + q * 4 + r) * 264 + col] = f2s(lrelu(acc[nt][1][r] + bias));
                s3[(32 + q * 4 + r) * 264 + col] = f2s(lrelu(acc[nt][2][r] + bias));
            }
        }
    }
    __syncthreads();

    {
        int vi = t >> 2, l = t & 3;
        if (vi < MTV) {
            float p0 = 0.f, p1 = 0.f, p2 = 0.f;
            for (int k = l * 8; k < 256; k += 32) {
                #pragma unroll
                for (int j = 0; j < 8; j++) {
                    float a = s2f(s3[vi * 264 + k + j]);
                    p0 += a * s2f(sW4[0 * 256 + k + j]);
                    p1 += a * s2f(sW4[1 * 256 + k + j]);
                    p2 += a * s2f(sW4[2 * 256 + k + j]);
                }
            }
            #pragma unroll
            for (int s = 2; s; s >>= 1) {
                p0 += __shfl_down(p0, s, 4);
                p1 += __shfl_down(p1, s, 4);
                p2 += __shfl_down(p2, s, 4);
            }
            if (l == 0) {
                int vert = perm ? perm[base + vi] : (base + vi);
                float vx = ldf(v, vert * 3 + 0, bf);
                float vy = ldf(v, vert * 3 + 1, bf);
                float vz = ldf(v, vert * 3 + 2, bf);
                float o0 = vx + 0.1f * tanhf(p0 + ldf(fc4_b, 0, bf));
                float o1 = vy + 0.1f * tanhf(p1 + ldf(fc4_b, 1, bf));
                float o2 = vz + 0.1f * tanhf(p2 + ldf(fc4_b, 2, bf));
                if (bf) {
                    short* ob = (short*)out;
                    ob[vert * 3 + 0] = f2s(o0);
                    ob[vert * 3 + 1] = f2s(o1);
                    ob[vert * 3 + 2] = f2s(o2);
                } else {
                    float* of = (float*)out;
                    of[vert * 3 + 0] = o0;
                    of[vert * 3 + 1] = o1;
                    of[vert * 3 + 2] = o2;
                }
            }
        }
    }
}

// ================= SMALL-WS FALLBACK: R10 monolith =================
__global__ __launch_bounds__(256, 3) void fused_mfma_kernel(
    const void* __restrict__ v,
    const float* __restrict__ n_accum,
    const void* __restrict__ volume,
    const short* __restrict__ vol1,
    const short* __restrict__ vol2,
    const short* __restrict__ Wcomb,
    const float* __restrict__ bcomb,
    const short* __restrict__ fc2T,
    const short* __restrict__ fc3T,
    const void* __restrict__ fc1_w, const void* __restrict__ fc1_b,
    const void* __restrict__ fc2_b, const void* __restrict__ fc3_b,
    const void* __restrict__ fc4_w, const void* __restrict__ fc4_b,
    void* __restrict__ out,
    const int* __restrict__ flag)
{
    __shared__ __align__(16) char smem[51712];
    short* sX    = (short*)smem;
    short* sCube = (short*)(smem + 16896);
    short* sH    = (short*)(smem + 16896);
    short* s3    = (short*)smem;
    short* sW4   = (short*)(smem + 50176);

    const int bf = *flag;
    const int t = threadIdx.x;
    const int base = blockIdx.x * TVB;
    const int w = t >> 6, L = t & 63, q = L >> 4, ln = L & 15;
    const int laneoff = (q * 16 + ln) * 8;

    for (int idx = t; idx < TVB * 75; idx += 256) {
        int vl  = idx / 75;
        int r75 = idx - vl * 75;
        int n   = r75 / 25;
        int dd  = r75 - n * 25;
        int di  = dd / 5, dj = dd - di * 5;
        int vert = base + vl;
        short* dst = &sCube[vl * 392 + n * 125 + dd * 5];
        if (vert < NVERT) {
            float vx = ldf(v, vert * 3 + 0, bf);
            float vy = ldf(v, vert * 3 + 1, bf);
            float vz = ldf(v, vert * 3 + 2, bf);
            float scl = (n == 0) ? 96.0f : (n == 1 ? 48.0f : 24.0f);
            int lim = (LVOL >> n) - 3;
            int cx = (int)rintf((vx + 1.0f) * scl);
            int cy = (int)rintf((vy + 1.0f) * scl);
            int cz = (int)rintf((vz + 1.0f) * scl);
            cx = min(max(cx, 2), lim) + di - 2;
            cy = min(max(cy, 2), lim) + dj - 2;
            cz = min(max(cz, 2), lim);
            if (n == 0) {
                int b0 = (cx * LVOL + cy) * LVOL + (cz - 2);
                if (bf) {
                    const short* vp = (const short*)volume;
                    #pragma unroll
                    for (int i = 0; i < 5; i++) dst[i] = vp[b0 + i];
                } else {
                    const float* vp = (const float*)volume;
                    #pragma unroll
                    for (int i = 0; i < 5; i++) dst[i] = f2s(vp[b0 + i]);
                }
            } else {
                const short* lvl = (n == 1) ? vol1 : vol2;
                int dim = (n == 1) ? 96 : 48;
                int b0 = (cx * dim + cy) * dim + (cz - 2);
                #pragma unroll
                for (int i = 0; i < 5; i++) dst[i] = lvl[b0 + i];
            }
        } else {
            #pragma unroll
            for (int i = 0; i < 5; i++) dst[i] = 0;
        }
    }
    for (int idx = t; idx < TVB * 9; idx += 256) {
        int vl = idx / 9, rr = idx - vl * 9;
        sCube[vl * 392 + 375 + rr] = 0;
    }
    for (int i = t; i < 768; i += 256) {
        int j = i >> 8, k = i & 255;
        sW4[i] = f2s(ldf(fc4_w, k * 3 + j, bf));
    }
    {
        int vi = t & 31, cb = (t >> 5) * 16;
        int vert = base + vi;
        float i0 = 0.f, i1 = 0.f, i2 = 0.f, i3 = 0.f, i4 = 0.f, i5 = 0.f;
        if (vert < NVERT) {
            i0 = ldf(v, vert * 3 + 0, bf);
            i1 = ldf(v, vert * 3 + 1, bf);
            i2 = ldf(v, vert * 3 + 2, bf);
            float nx = n_accum[vert * 3 + 0];
            float ny = n_accum[vert * 3 + 1];
            float nz = n_accum[vert * 3 + 2];
            float inv = 1.0f / fmaxf(sqrtf(nx * nx + ny * ny + nz * nz), 1e-12f);
            i3 = nx * inv; i4 = ny * inv; i5 = nz * inv;
        }
        #pragma unroll
        for (int i = 0; i < 16; i++) {
            int c = cb + i;
            float acc = ldf(fc1_b, c, bf)
                      + i0 * ldf(fc1_w, 0 * 128 + c, bf)
                      + i1 * ldf(fc1_w, 1 * 128 + c, bf)
                      + i2 * ldf(fc1_w, 2 * 128 + c, bf)
                      + i3 * ldf(fc1_w, 3 * 128 + c, bf)
                      + i4 * ldf(fc1_w, 4 * 128 + c, bf)
                      + i5 * ldf(fc1_w, 5 * 128 + c, bf);
            sX[vi * 264 + c] = f2s(lrelu(acc));
        }
    }
    __syncthreads();

    #pragma unroll
    for (int nt = 0; nt < 2; nt++) {
        int col = w * 32 + nt * 16 + ln;
        const short* wb = Wcomb + ((w * 2 + nt) * 12 * 64) * 8 + laneoff;
        v4f acc0 = {0.f, 0.f, 0.f, 0.f}, acc1 = {0.f, 0.f, 0.f, 0.f};
        #pragma unroll
        for (int k0 = 0; k0 < 12; k0++) {
            v8s b  = *(const v8s*)(wb + k0 * 512);
            v8s a0 = *(const v8s*)&sCube[ln * 392 + k0 * 32 + q * 8];
            v8s a1 = *(const v8s*)&sCube[(16 + ln) * 392 + k0 * 32 + q * 8];
            acc0 = __builtin_amdgcn_mfma_f32_16x16x32_bf16(a0, b, acc0, 0, 0, 0);
            acc1 = __builtin_amdgcn_mfma_f32_16x16x32_bf16(a1, b, acc1, 0, 0, 0);
        }
        float bias = bcomb[col];
        #pragma unroll
        for (int r = 0; r < 4; r++) {
            sX[(q * 4 + r) * 264 + 128 + col]      = f2s(acc0[r] + bias);
            sX[(16 + q * 4 + r) * 264 + 128 + col] = f2s(acc1[r] + bias);
        }
    }
    __syncthreads();

    {
        v8s a0[8], a1[8];
        #pragma unroll
        for (int k0 = 0; k0 < 8; k0++) {
            a0[k0] = *(const v8s*)&sX[ln * 264 + k0 * 32 + q * 8];
            a1[k0] = *(const v8s*)&sX[(16 + ln) * 264 + k0 * 32 + q * 8];
        }
        #pragma unroll
        for (int nt = 0; nt < 8; nt++) {
            int col = w * 128 + nt * 16 + ln;
            const short* bb = fc2T + (w * 8 + nt) * 8 * 512 + laneoff;
            v4f acc0 = {0.f, 0.f, 0.f, 0.f}, acc1 = {0.f, 0.f, 0.f, 0.f};
            #pragma unroll
            for (int k0 = 0; k0 < 8; k0++) {
                v8s b = *(const v8s*)(bb + k0 * 512);
                acc0 = __builtin_amdgcn_mfma_f32_16x16x32_bf16(a0[k0], b, acc0, 0, 0, 0);
                acc1 = __builtin_amdgcn_mfma_f32_16x16x32_bf16(a1[k0], b, acc1, 0, 0, 0);
            }
            float bias = ldf(fc2_b, col, bf);
            #pragma unroll
            for (int r = 0; r < 4; r++) {
                sH[(q * 4 + r) * 520 + col]      = f2s(lrelu(acc0[r] + bias));
                sH[(16 + q * 4 + r) * 520 + col] = f2s(lrelu(acc1[r] + bias));
            }
        }
    }
    __syncthreads();

    {
        #pragma unroll
        for (int nt = 0; nt < 4; nt++) {
            int col = w * 64 + nt * 16 + ln;
            v4f acc0 = {0.f, 0.f, 0.f, 0.f}, acc1 = {0.f, 0.f, 0.f, 0.f};
            #pragma unroll
            for (int half = 0; half < 2; half++) {
                const short* bb = fc3T + ((w * 4 + nt) * 16 + half * 8) * 512 + laneoff;
                #pragma unroll
                for (int k0 = 0; k0 < 8; k0++) {
                    v8s b  = *(const v8s*)(bb + k0 * 512);
                    v8s a0 = *(const v8s*)&sH[ln * 520 + half * 256 + k0 * 32 + q * 8];
                    v8s a1 = *(const v8s*)&sH[(16 + ln) * 520 + half * 256 + k0 * 32 + q * 8];
                    acc0 = __builtin_amdgcn_mfma_f32_16x16x32_bf16(a0, b, acc0, 0, 0, 0);
                    acc1 = __builtin_amdgcn_mfma_f32_16x16x32_bf16(a1, b, acc1, 0, 0, 0);
                }
            }
            float bias = ldf(fc3_b, col, bf);
            #pragma unroll
            for (int r = 0; r < 4; r++) {
                s3[(q * 4 + r) * 264 + col]      = f2s(lrelu(acc0[r] + bias));
                s3[(16 + q * 4 + r) * 264 + col] = f2s(lrelu(acc1[r] + bias));
            }
        }
    }
    __syncthreads();

    {
        int vi = t >> 3, l = t & 7;
        float p0 = 0.f, p1 = 0.f, p2 = 0.f;
        for (int k = l; k < 256; k += 8) {
            float a = s2f(s3[vi * 264 + k]);
            p0 += a * s2f(sW4[0 * 256 + k]);
            p1 += a * s2f(sW4[1 * 256 + k]);
            p2 += a * s2f(sW4[2 * 256 + k]);
        }
        #pragma unroll
        for (int s = 4; s; s >>= 1) {
            p0 += __shfl_down(p0, s, 8);
            p1 += __shfl_down(p1, s, 8);
            p2 += __shfl_down(p2, s, 8);
        }
        if (l == 0) {
            int vert = base + vi;
            if (vert < NVERT) {
                float vx = ldf(v, vert * 3 + 0, bf);
                float vy = ldf(v, vert * 3 + 1, bf);
                float vz = ldf(v, vert * 3 + 2, bf);
                float o0 = vx + 0.1f * tanhf(p0 + ldf(fc4_b, 0, bf));
                float o1 = vy + 0.1f * tanhf(p1 + ldf(fc4_b, 1, bf));
                float o2 = vz + 0.1f * tanhf(p2 + ldf(fc4_b, 2, bf));
                if (bf) {
                    short* ob = (short*)out;
                    ob[vert * 3 + 0] = f2s(o0);
                    ob[vert * 3 + 1] = f2s(o1);
                    ob[vert * 3 + 2] = f2s(o2);
                } else {
                    float* of = (float*)out;
                    of[vert * 3 + 0] = o0;
                    of[vert * 3 + 1] = o1;
                    of[vert * 3 + 2] = o2;
                }
            }
        }
    }
}

extern "C" void kernel_launch(void* const* d_in, const int* in_sizes, int n_in,
                              void* d_out, int out_size, void* d_ws, size_t ws_size,
                              hipStream_t stream) {
    const void* v      = d_in[0];
    const int*  f      = (const int*)d_in[1];
    const void* volume = d_in[2];
    const void* fc1_w  = d_in[3];
    const void* fc1_b  = d_in[4];
    const void* fc2_w  = d_in[5];
    const void* fc2_b  = d_in[6];
    const void* fc3_w  = d_in[7];
    const void* fc3_b  = d_in[8];
    const void* fc4_w  = d_in[9];
    const void* fc4_b  = d_in[10];
    const void* conv_w = d_in[11];
    const void* conv_b = d_in[12];
    const void* lfc_w  = d_in[13];
    const void* lfc_b  = d_in[14];

    char* wsb = (char*)d_ws;
    const int big  = (ws_size >= WS_BIG_NEED) ? 1 : 0;
    const int b16  = (ws_size >= WS_B16_NEED) ? 1 : 0;
    const int srt  = (ws_size >= WS_SORT_NEED) ? 1 : 0;

    if (big) {
        int*   flag    = (int*)wsb;
        float* n_accum = (float*)(wsb + 64);
        short* vol1b   = (short*)(wsb + 1800064);   // 96^3 bf16 (1,769,472 B)
        short* vol2b   = (short*)(wsb + 5339008);   // 48^3 bf16 (221,184 B)
        short* Wcomb   = (short*)(wsb + 5781376);
        float* bcomb   = (float*)(wsb + 5879680);
        short* fc2T    = (short*)(wsb + 5880192);
        short* fc3T    = (short*)(wsb + 6142336);
        short* xloc    = (short*)(wsb + 6404480);
        short* vol0b   = b16 ? (short*)(wsb + 44808576) : nullptr;  // 192^3 bf16
        int*   hist    = srt ? (int*)(wsb + 58964352) : nullptr;    // 13824 ints (-> cursor)
        int*   keys    = srt ? (int*)(wsb + 59019648) : nullptr;    // 150000 ints
        int*   perm    = srt ? (int*)(wsb + 59619648) : nullptr;    // 150000 ints

        hipMemsetAsync(n_accum, 0, NVERT * 3 * sizeof(float), stream);
        detect_kernel<<<1, 256, 0, stream>>>(v, flag);
        if (srt) {
            hipMemsetAsync(hist, 0, NBUCKET * sizeof(int), stream);
            sort_hist_kernel<<<(NVERT + 255) / 256, 256, 0, stream>>>(v, hist, keys, flag);
            sort_scan_kernel<<<1, 1024, 0, stream>>>(hist);
            sort_scatter_kernel<<<(NVERT + 255) / 256, 256, 0, stream>>>(hist, keys, perm);
        }
        mega_prep2_kernel<<<P2_CP0_START + (b16 ? P2_CP0 : 0), 256, 0, stream>>>(
            volume, vol1b, vol2b,
            conv_w, lfc_w, conv_b, lfc_b, Wcomb, bcomb, flag, vol0b);
        int ngather = (NVERT + TVB - 1) / TVB;
        gather_ext_kernel<<<ngather + NB_NORM + NB_TRS, 256, 0, stream>>>(
            v, f, n_accum, volume, vol1b, vol2b, vol0b, perm, Wcomb, bcomb,
            fc2_w, fc3_w, fc2T, fc3T, xloc, flag, ngather);
        mlp_kernel<<<(NVERT + MTV - 1) / MTV, 256, 0, stream>>>(
            v, n_accum, xloc, perm, fc2T, fc3T,
            fc1_w, fc1_b, fc2_b, fc3_b, fc4_w, fc4_b, d_out, flag);
    } else {
        int*   flag    = (int*)wsb;
        float* n_accum = (float*)(wsb + 64);
        short* vol1    = (short*)(wsb + 1800064);
        short* vol2    = (short*)(wsb + 3569536);
        short* Wcomb   = (short*)(wsb + 3790720);
        float* bcomb   = (float*)(wsb + 3889024);
        short* fc2T    = (short*)(wsb + 3889536);
        short* fc3T    = (short*)(wsb + 4151680);

        hipMemsetAsync(n_accum, 0, NVERT * 3 * sizeof(float), stream);
        detect_kernel<<<1, 256, 0, stream>>>(v, flag);
        mega_prep2_kernel<<<P2_CP0_START, 256, 0, stream>>>(
            volume, vol1, vol2,
            conv_w, lfc_w, conv_b, lfc_b, Wcomb, bcomb, flag, nullptr);
        gather_ext_kernel<<<NB_NORM + NB_TRS, 256, 0, stream>>>(
            v, f, n_accum, volume, vol1, vol2, nullptr, nullptr, Wcomb, bcomb,
            fc2_w, fc3_w, fc2T, fc3T, nullptr, flag, 0);
        fused_mfma_kernel<<<(NVERT + TVB - 1) / TVB, 256, 0, stream>>>(
            v, n_accum, volume, vol1, vol2, Wcomb, bcomb, fc2T, fc3T,
            fc1_w, fc1_b, fc2_b, fc3_b, fc4_w, fc4_b, d_out, flag);
    }
}

// Round 12
// 550.571 us; speedup vs baseline: 1.0102x; 1.0102x over previous
//
#include <hip/hip_runtime.h>
#include <hip/hip_bf16.h>
#include <math.h>

#define NVERT 150000
#define NFACE 300000
#define LVOL  192
#define TVB   32
#define MTV   48      // vertices per block in mlp kernel (M = 3 MFMA rows)

// mega_prep2 block-range partition
#define P2_POOL1 3456
#define P2_POOL2 432
#define P2_WC    193
#define P2_WC8   304
#define P2_CP0   3456
#define P2_POOL2_START (P2_POOL1)
#define P2_WC_START    (P2_POOL1 + P2_POOL2)
#define P2_WC8_START   (P2_WC_START + P2_WC)
#define P2_CP0_START   (P2_WC8_START + P2_WC8)

// extra blocks appended to gather grid (mlp-only prerequisites)
#define NB_NORM 1172
#define NB_TRS  1024

#define NBUCKET 13824     // 24^3 cells of 8^3 voxels
#define WS_BIG_NEED  44808576ull
#define WS_B16_NEED  58964352ull   // + 14,155,776 B for vol0b (192^3 bf16)
#define WS_SORT_NEED 60219648ull   // + hist(55,296) + keys(600,000) + perm(600,000)

typedef short v8s __attribute__((ext_vector_type(8)));
typedef float v4f __attribute__((ext_vector_type(4)));
typedef unsigned int v4u __attribute__((ext_vector_type(4)));

__device__ __forceinline__ float s2f(short s) {
    unsigned int u = ((unsigned int)(unsigned short)s) << 16;
    return __builtin_bit_cast(float, u);
}
__device__ __forceinline__ short f2s(float f) {
    __hip_bfloat16 h = __float2bfloat16(f);
    return __builtin_bit_cast(short, h);
}
__device__ __forceinline__ float lrelu(float x) { return x > 0.f ? x : 0.15f * x; }

__device__ __forceinline__ float ldf(const void* __restrict__ p, int i, int bf) {
    return bf ? s2f(((const short*)p)[i]) : ((const float*)p)[i];
}

// Banked H addressing (shorts): col c in [0,512), row r in [0,48).
__device__ __forceinline__ int haddr(int r, int c) {
    int hi  = c >> 7;
    int mid = (c >> 4) & 7;
    int lo  = c & 15;
    int wc  = hi * 64 + (mid & 3) * 16 + lo;
    return ((mid < 4) ? 0 : 12672) + r * 264 + wc;
}

// ---- detect input dtype (bf16 vs fp32) ----
__global__ void detect_kernel(const void* __restrict__ v, int* __restrict__ flag) {
    __shared__ int s_ok;
    int t = threadIdx.x;
    if (t == 0) s_ok = 1;
    __syncthreads();
    float x = s2f(((const short*)v)[t]);
    if (!(fabsf(x) <= 1.0f)) atomicAnd(&s_ok, 0);
    __syncthreads();
    if (t == 0) *flag = s_ok;
}

// ---- spatial counting sort (3 kernels) ----
__global__ __launch_bounds__(256) void sort_hist_kernel(
    const void* __restrict__ v, int* __restrict__ hist, int* __restrict__ keys,
    const int* __restrict__ flag)
{
    const int bf = *flag;
    int vert = blockIdx.x * 256 + threadIdx.x;
    if (vert >= NVERT) return;
    float vx = ldf(v, vert * 3 + 0, bf);
    float vy = ldf(v, vert * 3 + 1, bf);
    float vz = ldf(v, vert * 3 + 2, bf);
    int cx = min(max((int)rintf((vx + 1.0f) * 96.0f), 2), 189);
    int cy = min(max((int)rintf((vy + 1.0f) * 96.0f), 2), 189);
    int cz = min(max((int)rintf((vz + 1.0f) * 96.0f), 2), 189);
    int key = ((cx >> 3) * 24 + (cy >> 3)) * 24 + (cz >> 3);
    keys[vert] = key;
    atomicAdd(&hist[key], 1);
}

__global__ __launch_bounds__(1024) void sort_scan_kernel(int* __restrict__ hist)
{
    __shared__ int partial[1024];
    const int t = threadIdx.x;
    const int CH = 14;
    int base = t * CH;
    int sum = 0;
    #pragma unroll
    for (int i = 0; i < CH; i++) {
        int idx = base + i;
        if (idx < NBUCKET) sum += hist[idx];
    }
    partial[t] = sum;
    __syncthreads();
    for (int off = 1; off < 1024; off <<= 1) {
        int x = (t >= off) ? partial[t - off] : 0;
        __syncthreads();
        partial[t] += x;
        __syncthreads();
    }
    int run = partial[t] - sum;
    for (int i = 0; i < CH; i++) {
        int idx = base + i;
        if (idx < NBUCKET) {
            int c = hist[idx];
            hist[idx] = run;
            run += c;
        }
    }
}

__global__ __launch_bounds__(256) void sort_scatter_kernel(
    int* __restrict__ cursor, const int* __restrict__ keys, int* __restrict__ perm)
{
    int vert = blockIdx.x * 256 + threadIdx.x;
    if (vert >= NVERT) return;
    int pos = atomicAdd(&cursor[keys[vert]], 1);
    perm[pos] = vert;
}

// ---------------- mega_prep2: pools | Wcomb384 | Wcomb8(K=608) | [vol0b] ----
// Wcomb8: cube rows padded 5->8 shorts (K=608=19x32) so the gather's copy is
// 3 dword loads + 1 ds_write_b128 per run instead of 5 scalar loads + 5 writes.
__global__ __launch_bounds__(256) void mega_prep2_kernel(
    const void* __restrict__ volume,
    short* __restrict__ vol1b, short* __restrict__ vol2b,
    const void* __restrict__ conv_w, const void* __restrict__ lfc_w,
    const void* __restrict__ conv_b, const void* __restrict__ lfc_b,
    short* __restrict__ Wcomb, short* __restrict__ Wcomb8, float* __restrict__ bcomb,
    const int* __restrict__ flag,
    short* __restrict__ vol0b)
{
    const int bf = *flag;
    const int bid = blockIdx.x;
    const int t = threadIdx.x;

    if (bid < P2_POOL1) {
        int id = bid * 256 + t;
        int z = id % 96, y = (id / 96) % 96, x = id / (96 * 96);
        float s = 0.f;
        #pragma unroll
        for (int a = 0; a < 2; a++)
            #pragma unroll
            for (int b = 0; b < 2; b++)
                #pragma unroll
                for (int c = 0; c < 2; c++)
                    s += ldf(volume, (2 * x + a) * (LVOL * LVOL) + (2 * y + b) * LVOL + (2 * z + c), bf);
        s *= 0.125f;
        vol1b[id] = f2s(s);
    } else if (bid < P2_WC_START) {
        int id = (bid - P2_POOL2_START) * 256 + t;
        int z = id % 48, y = (id / 48) % 48, x = id / (48 * 48);
        float s = 0.f;
        for (int a = 0; a < 4; a++)
            for (int b = 0; b < 4; b++)
                #pragma unroll
                for (int c = 0; c < 4; c++)
                    s += ldf(volume, (4 * x + a) * (LVOL * LVOL) + (4 * y + b) * LVOL + (4 * z + c), bf);
        s *= 0.015625f;
        vol2b[id] = f2s(s);
    } else if (bid < P2_WC8_START) {
        int id = (bid - P2_WC_START) * 256 + t;
        if (id < 49152) {
            int j = id / 384, k = id - j * 384;
            float acc = 0.f;
            if (k < 375) {
                float a0 = 0.f, a1 = 0.f, a2 = 0.f, a3 = 0.f;
                for (int o = 0; o < 128; o += 4) {
                    a0 += ldf(conv_w, (o + 0) * 375 + k, bf) * ldf(lfc_w, (o + 0) * 128 + j, bf);
                    a1 += ldf(conv_w, (o + 1) * 375 + k, bf) * ldf(lfc_w, (o + 1) * 128 + j, bf);
                    a2 += ldf(conv_w, (o + 2) * 375 + k, bf) * ldf(lfc_w, (o + 2) * 128 + j, bf);
                    a3 += ldf(conv_w, (o + 3) * 375 + k, bf) * ldf(lfc_w, (o + 3) * 128 + j, bf);
                }
                acc = (a0 + a1) + (a2 + a3);
            }
            int tile = j >> 4, ln = j & 15;
            int kk = k >> 5, r = k & 31, qq = r >> 3, e = r & 7;
            Wcomb[((tile * 12 + kk) * 64 + qq * 16 + ln) * 8 + e] = f2s(acc);
        } else if (id < 49152 + 128) {
            int j = id - 49152;
            float acc = ldf(lfc_b, j, bf);
            for (int o = 0; o < 128; o++) acc += ldf(conv_b, o, bf) * ldf(lfc_w, o * 128 + j, bf);
            bcomb[j] = acc;
        }
    } else if (bid < P2_CP0_START) {
        // Wcomb8: K=608 layout; k = r*8 + e (r<75 real rows, e<5 real elems)
        int id = (bid - P2_WC8_START) * 256 + t;    // 304*256 = 77824 exactly
        int j = id / 608, k = id - j * 608;
        int r = k >> 3, e = k & 7;
        float acc = 0.f;
        if (e < 5 && r < 75) {
            int k375 = (r / 25) * 125 + (r % 25) * 5 + e;
            float a0 = 0.f, a1 = 0.f, a2 = 0.f, a3 = 0.f;
            for (int o = 0; o < 128; o += 4) {
                a0 += ldf(conv_w, (o + 0) * 375 + k375, bf) * ldf(lfc_w, (o + 0) * 128 + j, bf);
                a1 += ldf(conv_w, (o + 1) * 375 + k375, bf) * ldf(lfc_w, (o + 1) * 128 + j, bf);
                a2 += ldf(conv_w, (o + 2) * 375 + k375, bf) * ldf(lfc_w, (o + 2) * 128 + j, bf);
                a3 += ldf(conv_w, (o + 3) * 375 + k375, bf) * ldf(lfc_w, (o + 3) * 128 + j, bf);
            }
            acc = (a0 + a1) + (a2 + a3);
        }
        int tile = j >> 4, ln = j & 15;
        int kk = k >> 5, rr = k & 31, qq = rr >> 3, ee = rr & 7;
        Wcomb8[((tile * 19 + kk) * 64 + qq * 16 + ln) * 8 + ee] = f2s(acc);
    } else {
        if (bf) return;
        int id = (bid - P2_CP0_START) * 2048 + t * 8;
        const float* vp = (const float*)volume;
        short tmp[8];
        #pragma unroll
        for (int i = 0; i < 8; i++) tmp[i] = f2s(vp[id + i]);
        *(v8s*)&vol0b[id] = *(v8s*)tmp;
    }
}

// ================= gather8: K=608 vectorized gather (srt path) =================
// Per 5-elem run: 3 dword loads (align-fixed) + shifts + 1 ds_write_b128.
// xloc written in SLOT order; mlp maps slot->vert via perm.
__global__ __launch_bounds__(256, 4) void gather8_kernel(
    const void* __restrict__ v,
    const int* __restrict__ f, float* __restrict__ n_accum,
    const void* __restrict__ volume,
    const short* __restrict__ vol1b,
    const short* __restrict__ vol2b,
    const short* __restrict__ vol0b,
    const int* __restrict__ perm,
    const short* __restrict__ Wcomb8,
    const float* __restrict__ bcomb,
    const void* __restrict__ fc2_w, const void* __restrict__ fc3_w,
    short* __restrict__ fc2T, short* __restrict__ fc3T,
    short* __restrict__ xloc,
    const int* __restrict__ flag, int ngather)
{
    __shared__ __align__(16) short sCube[TVB * 608];   // 38,912 B
    __shared__ int sIdx[TVB * 4];

    const int bf = *flag;
    const int t = threadIdx.x;
    const int bid = blockIdx.x;

    if (bid >= ngather) {
        int rb = bid - ngather;
        if (rb < NB_NORM) {
            int ft = rb * 256 + t;
            if (ft >= NFACE) return;
            int i0 = f[ft * 3 + 0], i1 = f[ft * 3 + 1], i2 = f[ft * 3 + 2];
            float p0x = ldf(v, i0 * 3 + 0, bf), p0y = ldf(v, i0 * 3 + 1, bf), p0z = ldf(v, i0 * 3 + 2, bf);
            float p1x = ldf(v, i1 * 3 + 0, bf), p1y = ldf(v, i1 * 3 + 1, bf), p1z = ldf(v, i1 * 3 + 2, bf);
            float p2x = ldf(v, i2 * 3 + 0, bf), p2y = ldf(v, i2 * 3 + 1, bf), p2z = ldf(v, i2 * 3 + 2, bf);
            float e1x = p1x - p0x, e1y = p1y - p0y, e1z = p1z - p0z;
            float e2x = p2x - p0x, e2y = p2y - p0y, e2z = p2z - p0z;
            float cx = e1y * e2z - e1z * e2y;
            float cy = e1z * e2x - e1x * e2z;
            float cz = e1x * e2y - e1y * e2x;
            atomicAdd(&n_accum[i0 * 3 + 0], cx); atomicAdd(&n_accum[i0 * 3 + 1], cy); atomicAdd(&n_accum[i0 * 3 + 2], cz);
            atomicAdd(&n_accum[i1 * 3 + 0], cx); atomicAdd(&n_accum[i1 * 3 + 1], cy); atomicAdd(&n_accum[i1 * 3 + 2], cz);
            atomicAdd(&n_accum[i2 * 3 + 0], cx); atomicAdd(&n_accum[i2 * 3 + 1], cy); atomicAdd(&n_accum[i2 * 3 + 2], cz);
        } else {
            int id = (rb - NB_NORM) * 256 + t;
            if (id < 131072) {
                int col = id >> 8, k = id & 255;
                int tile = col >> 4, ln = col & 15;
                int kk = k >> 5, r = k & 31, qq = r >> 3, e = r & 7;
                fc2T[((tile * 8 + kk) * 64 + qq * 16 + ln) * 8 + e] = f2s(ldf(fc2_w, k * 512 + col, bf));
            } else {
                int i = id - 131072;
                int col = i >> 9, k = i & 511;
                int tile = col >> 4, ln = col & 15;
                int kk = k >> 5, r = k & 31, qq = r >> 3, e = r & 7;
                fc3T[((tile * 16 + kk) * 64 + qq * 16 + ln) * 8 + e] = f2s(ldf(fc3_w, k * 256 + col, bf));
            }
        }
        return;
    }

    const int base = bid * TVB;
    const int w = t >> 6, L = t & 63, q = L >> 4, ln = L & 15;
    const short* v0 = bf ? (const short*)volume : vol0b;

    if (t < TVB) {
        int slot = min(base + t, NVERT - 1);
        int vert = perm ? perm[slot] : slot;
        float vx = ldf(v, vert * 3 + 0, bf);
        float vy = ldf(v, vert * 3 + 1, bf);
        float vz = ldf(v, vert * 3 + 2, bf);
        #pragma unroll
        for (int n = 0; n < 3; n++) {
            float scl = (n == 0) ? 96.0f : (n == 1 ? 48.0f : 24.0f);
            int dim = LVOL >> n, lim = dim - 3;
            int cx = min(max((int)rintf((vx + 1.0f) * scl), 2), lim);
            int cy = min(max((int)rintf((vy + 1.0f) * scl), 2), lim);
            int cz = min(max((int)rintf((vz + 1.0f) * scl), 2), lim);
            sIdx[t * 4 + n] = (cx * dim + cy) * dim + (cz - 2);
        }
        // zero tail rows k=600..607 for this vertex
        *(v4u*)&sCube[t * 608 + 600] = (v4u){0u, 0u, 0u, 0u};
    }
    __syncthreads();

    for (int idx = t; idx < TVB * 75; idx += 256) {
        int n   = idx / 800;
        int rem = idx - n * 800;
        int vl  = rem / 25;
        int dd  = rem - vl * 25;
        int di  = dd / 5, dj = dd - di * 5;
        int dim = LVOL >> n;
        int addr = sIdx[vl * 4 + n] + (di - 2) * dim * dim + (dj - 2) * dim;
        int r = n * 25 + dd;
        if (n == 0 && bf) {
            // bf16 INPUT volume (can't guarantee slack): scalar fallback
            const short* vp = (const short*)volume;
            short* dst = &sCube[vl * 608 + r * 8];
            #pragma unroll
            for (int i = 0; i < 5; i++) dst[i] = vp[addr + i];
            dst[5] = 0; dst[6] = 0; dst[7] = 0;
        } else {
            const short* lvl = (n == 0) ? v0 : (n == 1 ? vol1b : vol2b);
            int p  = addr & 1;
            int a0 = addr - p;
            const unsigned int* u = (const unsigned int*)(lvl + a0);   // 4B-aligned
            unsigned int x0 = u[0], x1 = u[1], x2 = u[2];              // shorts s0..s5
            unsigned int d0, d1, d2;
            if (p) {
                d0 = (x0 >> 16) | (x1 << 16);
                d1 = (x1 >> 16) | (x2 << 16);
                d2 = (x2 >> 16);
            } else {
                d0 = x0;
                d1 = x1;
                d2 = x2 & 0xFFFFu;
            }
            *(v4u*)&sCube[vl * 608 + r * 8] = (v4u){d0, d1, d2, 0u};
        }
    }
    __syncthreads();

    #pragma unroll
    for (int nt = 0; nt < 2; nt++) {
        int col = w * 32 + nt * 16 + ln;
        const short* wb = Wcomb8 + ((w * 2 + nt) * 19 * 64 + q * 16 + ln) * 8;
        v4f acc0 = {0.f, 0.f, 0.f, 0.f}, acc1 = {0.f, 0.f, 0.f, 0.f};
        #pragma unroll
        for (int k0 = 0; k0 < 19; k0++) {
            v8s b  = *(const v8s*)(wb + k0 * 512);
            v8s a0 = *(const v8s*)&sCube[ln * 608 + k0 * 32 + q * 8];
            v8s a1 = *(const v8s*)&sCube[(16 + ln) * 608 + k0 * 32 + q * 8];
            acc0 = __builtin_amdgcn_mfma_f32_16x16x32_bf16(a0, b, acc0, 0, 0, 0);
            acc1 = __builtin_amdgcn_mfma_f32_16x16x32_bf16(a1, b, acc1, 0, 0, 0);
        }
        float bias = bcomb[col];
        #pragma unroll
        for (int r = 0; r < 4; r++) {
            xloc[(base + q * 4 + r) * 128 + col]      = f2s(acc0[r] + bias);
            xloc[(base + 16 + q * 4 + r) * 128 + col] = f2s(acc1[r] + bias);
        }
    }
}

// ================= gather_ext (K=384): fallback when sort workspace absent ======
__global__ __launch_bounds__(256, 6) void gather_ext_kernel(
    const void* __restrict__ v,
    const int* __restrict__ f, float* __restrict__ n_accum,
    const void* __restrict__ volume,
    const short* __restrict__ vol1b,
    const short* __restrict__ vol2b,
    const short* __restrict__ vol0b,
    const int* __restrict__ perm,
    const short* __restrict__ Wcomb,
    const float* __restrict__ bcomb,
    const void* __restrict__ fc2_w, const void* __restrict__ fc3_w,
    short* __restrict__ fc2T, short* __restrict__ fc3T,
    short* __restrict__ xloc,
    const int* __restrict__ flag, int ngather)
{
    __shared__ __align__(16) short sCube[TVB * 392];
    __shared__ int sIdx[TVB * 4];

    const int bf = *flag;
    const int t = threadIdx.x;
    const int bid = blockIdx.x;

    if (bid >= ngather) {
        int rb = bid - ngather;
        if (rb < NB_NORM) {
            int ft = rb * 256 + t;
            if (ft >= NFACE) return;
            int i0 = f[ft * 3 + 0], i1 = f[ft * 3 + 1], i2 = f[ft * 3 + 2];
            float p0x = ldf(v, i0 * 3 + 0, bf), p0y = ldf(v, i0 * 3 + 1, bf), p0z = ldf(v, i0 * 3 + 2, bf);
            float p1x = ldf(v, i1 * 3 + 0, bf), p1y = ldf(v, i1 * 3 + 1, bf), p1z = ldf(v, i1 * 3 + 2, bf);
            float p2x = ldf(v, i2 * 3 + 0, bf), p2y = ldf(v, i2 * 3 + 1, bf), p2z = ldf(v, i2 * 3 + 2, bf);
            float e1x = p1x - p0x, e1y = p1y - p0y, e1z = p1z - p0z;
            float e2x = p2x - p0x, e2y = p2y - p0y, e2z = p2z - p0z;
            float cx = e1y * e2z - e1z * e2y;
            float cy = e1z * e2x - e1x * e2z;
            float cz = e1x * e2y - e1y * e2x;
            atomicAdd(&n_accum[i0 * 3 + 0], cx); atomicAdd(&n_accum[i0 * 3 + 1], cy); atomicAdd(&n_accum[i0 * 3 + 2], cz);
            atomicAdd(&n_accum[i1 * 3 + 0], cx); atomicAdd(&n_accum[i1 * 3 + 1], cy); atomicAdd(&n_accum[i1 * 3 + 2], cz);
            atomicAdd(&n_accum[i2 * 3 + 0], cx); atomicAdd(&n_accum[i2 * 3 + 1], cy); atomicAdd(&n_accum[i2 * 3 + 2], cz);
        } else {
            int id = (rb - NB_NORM) * 256 + t;
            if (id < 131072) {
                int col = id >> 8, k = id & 255;
                int tile = col >> 4, ln = col & 15;
                int kk = k >> 5, r = k & 31, qq = r >> 3, e = r & 7;
                fc2T[((tile * 8 + kk) * 64 + qq * 16 + ln) * 8 + e] = f2s(ldf(fc2_w, k * 512 + col, bf));
            } else {
                int i = id - 131072;
                int col = i >> 9, k = i & 511;
                int tile = col >> 4, ln = col & 15;
                int kk = k >> 5, r = k & 31, qq = r >> 3, e = r & 7;
                fc3T[((tile * 16 + kk) * 64 + qq * 16 + ln) * 8 + e] = f2s(ldf(fc3_w, k * 256 + col, bf));
            }
        }
        return;
    }

    const int base = bid * TVB;
    const int w = t >> 6, L = t & 63, q = L >> 4, ln = L & 15;
    const short* v0 = bf ? (const short*)volume : vol0b;

    if (t < TVB) {
        int slot = min(base + t, NVERT - 1);
        int vert = perm ? perm[slot] : slot;
        float vx = ldf(v, vert * 3 + 0, bf);
        float vy = ldf(v, vert * 3 + 1, bf);
        float vz = ldf(v, vert * 3 + 2, bf);
        #pragma unroll
        for (int n = 0; n < 3; n++) {
            float scl = (n == 0) ? 96.0f : (n == 1 ? 48.0f : 24.0f);
            int dim = LVOL >> n, lim = dim - 3;
            int cx = min(max((int)rintf((vx + 1.0f) * scl), 2), lim);
            int cy = min(max((int)rintf((vy + 1.0f) * scl), 2), lim);
            int cz = min(max((int)rintf((vz + 1.0f) * scl), 2), lim);
            sIdx[t * 4 + n] = (cx * dim + cy) * dim + (cz - 2);
        }
    }
    __syncthreads();

    for (int idx = t; idx < TVB * 75; idx += 256) {
        int n   = idx / 800;
        int rem = idx - n * 800;
        int vl  = rem / 25;
        int dd  = rem - vl * 25;
        int di  = dd / 5, dj = dd - di * 5;
        int dim = LVOL >> n;
        int addr = sIdx[vl * 4 + n] + (di - 2) * dim * dim + (dj - 2) * dim;
        short* dst = &sCube[vl * 392 + n * 125 + dd * 5];
        if (n == 0 && v0 == nullptr) {
            const float* vp = (const float*)volume;
            #pragma unroll
            for (int i = 0; i < 5; i++) dst[i] = f2s(vp[addr + i]);
        } else {
            const short* lvl = (n == 0) ? v0 : (n == 1 ? vol1b : vol2b);
            #pragma unroll
            for (int i = 0; i < 5; i++) dst[i] = lvl[addr + i];
        }
    }
    for (int idx = t; idx < TVB * 9; idx += 256) {
        int vl = idx / 9, rr = idx - vl * 9;
        sCube[vl * 392 + 375 + rr] = 0;
    }
    __syncthreads();

    #pragma unroll
    for (int nt = 0; nt < 2; nt++) {
        int col = w * 32 + nt * 16 + ln;
        const short* wb = Wcomb + ((w * 2 + nt) * 12 * 64 + q * 16 + ln) * 8;
        v4f acc0 = {0.f, 0.f, 0.f, 0.f}, acc1 = {0.f, 0.f, 0.f, 0.f};
        #pragma unroll
        for (int k0 = 0; k0 < 12; k0++) {
            v8s b  = *(const v8s*)(wb + k0 * 512);
            v8s a0 = *(const v8s*)&sCube[ln * 392 + k0 * 32 + q * 8];
            v8s a1 = *(const v8s*)&sCube[(16 + ln) * 392 + k0 * 32 + q * 8];
            acc0 = __builtin_amdgcn_mfma_f32_16x16x32_bf16(a0, b, acc0, 0, 0, 0);
            acc1 = __builtin_amdgcn_mfma_f32_16x16x32_bf16(a1, b, acc1, 0, 0, 0);
        }
        float bias = bcomb[col];
        #pragma unroll
        for (int r = 0; r < 4; r++) {
            xloc[(base + q * 4 + r) * 128 + col]      = f2s(acc0[r] + bias);
            xloc[(base + 16 + q * 4 + r) * 128 + col] = f2s(acc1[r] + bias);
        }
    }
}

// ---- kernel B: MLP, 48 slots/block (M=3 MFMA rows) ----  [UNCHANGED — control]
__global__ __launch_bounds__(256, 3) void mlp_kernel(
    const void* __restrict__ v,
    const float* __restrict__ n_accum,
    const short* __restrict__ xloc,
    const int* __restrict__ perm,
    const short* __restrict__ fc2T,
    const short* __restrict__ fc3T,
    const void* __restrict__ fc1_w, const void* __restrict__ fc1_b,
    const void* __restrict__ fc2_b, const void* __restrict__ fc3_b,
    const void* __restrict__ fc4_w, const void* __restrict__ fc4_b,
    void* __restrict__ out,
    const int* __restrict__ flag)
{
    __shared__ __align__(16) char smem[52224];
    short* sX  = (short*)smem;
    short* sHB = (short*)smem;
    short* s3  = (short*)smem;
    short* sW4 = (short*)(smem + 50688);

    const int bf = *flag;
    const int t = threadIdx.x;
    const int base = blockIdx.x * MTV;
    const int w = t >> 6, L = t & 63, q = L >> 4, ln = L & 15;
    const int laneoff = (q * 16 + ln) * 8;

    for (int id = t; id < MTV * 16; id += 256) {
        int row = id >> 4, seg = id & 15;
        v8s x = *(const v8s*)(xloc + (base + row) * 128 + seg * 8);
        *(v8s*)&sX[row * 264 + 128 + seg * 8] = x;
    }

    for (int i = t; i < 768; i += 256) {
        int j = i >> 8, k = i & 255;
        sW4[i] = f2s(ldf(fc4_w, k * 3 + j, bf));
    }

    {
        int vi = t >> 2, cb = (t & 3) * 32;
        if (vi < MTV) {
            int vert = perm ? perm[base + vi] : (base + vi);
            float i0 = ldf(v, vert * 3 + 0, bf);
            float i1 = ldf(v, vert * 3 + 1, bf);
            float i2 = ldf(v, vert * 3 + 2, bf);
            float nx = n_accum[vert * 3 + 0];
            float ny = n_accum[vert * 3 + 1];
            float nz = n_accum[vert * 3 + 2];
            float inv = 1.0f / fmaxf(sqrtf(nx * nx + ny * ny + nz * nz), 1e-12f);
            float i3 = nx * inv, i4 = ny * inv, i5 = nz * inv;
            #pragma unroll 8
            for (int i = 0; i < 32; i++) {
                int c = cb + i;
                float acc = ldf(fc1_b, c, bf)
                          + i0 * ldf(fc1_w, 0 * 128 + c, bf)
                          + i1 * ldf(fc1_w, 1 * 128 + c, bf)
                          + i2 * ldf(fc1_w, 2 * 128 + c, bf)
                          + i3 * ldf(fc1_w, 3 * 128 + c, bf)
                          + i4 * ldf(fc1_w, 4 * 128 + c, bf)
                          + i5 * ldf(fc1_w, 5 * 128 + c, bf);
                sX[vi * 264 + c] = f2s(lrelu(acc));
            }
        }
    }
    __syncthreads();

    {
        #pragma unroll
        for (int nt = 4; nt < 8; nt++) {
            int col = w * 128 + nt * 16 + ln;
            const short* bb = fc2T + (w * 8 + nt) * 8 * 512 + laneoff;
            v4f acc0 = {0.f, 0.f, 0.f, 0.f}, acc1 = {0.f, 0.f, 0.f, 0.f}, acc2 = {0.f, 0.f, 0.f, 0.f};
            #pragma unroll
            for (int k0 = 0; k0 < 8; k0++) {
                v8s b  = *(const v8s*)(bb + k0 * 512);
                v8s a0 = *(const v8s*)&sX[(ln) * 264 + k0 * 32 + q * 8];
                v8s a1 = *(const v8s*)&sX[(16 + ln) * 264 + k0 * 32 + q * 8];
                v8s a2 = *(const v8s*)&sX[(32 + ln) * 264 + k0 * 32 + q * 8];
                acc0 = __builtin_amdgcn_mfma_f32_16x16x32_bf16(a0, b, acc0, 0, 0, 0);
                acc1 = __builtin_amdgcn_mfma_f32_16x16x32_bf16(a1, b, acc1, 0, 0, 0);
                acc2 = __builtin_amdgcn_mfma_f32_16x16x32_bf16(a2, b, acc2, 0, 0, 0);
            }
            float bias = ldf(fc2_b, col, bf);
            int wc = 12672 + w * 64 + (nt - 4) * 16 + ln;
            #pragma unroll
            for (int r = 0; r < 4; r++) {
                sHB[(q * 4 + r) * 264 + wc]      = f2s(lrelu(acc0[r] + bias));
                sHB[(16 + q * 4 + r) * 264 + wc] = f2s(lrelu(acc1[r] + bias));
                sHB[(32 + q * 4 + r) * 264 + wc] = f2s(lrelu(acc2[r] + bias));
            }
        }

        v4f accL[4][3];
        #pragma unroll
        for (int nt = 0; nt < 4; nt++)
            #pragma unroll
            for (int m = 0; m < 3; m++)
                accL[nt][m] = (v4f){0.f, 0.f, 0.f, 0.f};

        #pragma unroll
        for (int nt = 0; nt < 4; nt++) {
            const short* bb = fc2T + (w * 8 + nt) * 8 * 512 + laneoff;
            #pragma unroll
            for (int k0 = 0; k0 < 8; k0++) {
                v8s b  = *(const v8s*)(bb + k0 * 512);
                v8s a0 = *(const v8s*)&sX[(ln) * 264 + k0 * 32 + q * 8];
                v8s a1 = *(const v8s*)&sX[(16 + ln) * 264 + k0 * 32 + q * 8];
                v8s a2 = *(const v8s*)&sX[(32 + ln) * 264 + k0 * 32 + q * 8];
                accL[nt][0] = __builtin_amdgcn_mfma_f32_16x16x32_bf16(a0, b, accL[nt][0], 0, 0, 0);
                accL[nt][1] = __builtin_amdgcn_mfma_f32_16x16x32_bf16(a1, b, accL[nt][1], 0, 0, 0);
                accL[nt][2] = __builtin_amdgcn_mfma_f32_16x16x32_bf16(a2, b, accL[nt][2], 0, 0, 0);
            }
        }
        __syncthreads();

        #pragma unroll
        for (int nt = 0; nt < 4; nt++) {
            int col = w * 128 + nt * 16 + ln;
            float bias = ldf(fc2_b, col, bf);
            int wc = w * 64 + nt * 16 + ln;
            #pragma unroll
            for (int r = 0; r < 4; r++) {
                sHB[(q * 4 + r) * 264 + wc]      = f2s(lrelu(accL[nt][0][r] + bias));
                sHB[(16 + q * 4 + r) * 264 + wc] = f2s(lrelu(accL[nt][1][r] + bias));
                sHB[(32 + q * 4 + r) * 264 + wc] = f2s(lrelu(accL[nt][2][r] + bias));
            }
        }
    }
    __syncthreads();

    {
        v4f acc[4][3];
        #pragma unroll
        for (int nt = 0; nt < 4; nt++)
            #pragma unroll
            for (int m = 0; m < 3; m++)
                acc[nt][m] = (v4f){0.f, 0.f, 0.f, 0.f};

        #pragma unroll
        for (int half = 0; half < 2; half++) {
            v8s A0[8], A1[8], A2[8];
            #pragma unroll
            for (int k0 = 0; k0 < 8; k0++) {
                int c = half * 256 + k0 * 32 + q * 8;
                A0[k0] = *(const v8s*)&sHB[haddr(ln, c)];
                A1[k0] = *(const v8s*)&sHB[haddr(16 + ln, c)];
                A2[k0] = *(const v8s*)&sHB[haddr(32 + ln, c)];
            }
            #pragma unroll
            for (int nt = 0; nt < 4; nt++) {
                const short* bb = fc3T + ((w * 4 + nt) * 16 + half * 8) * 512 + laneoff;
                v8s B[8];
                #pragma unroll
                for (int k0 = 0; k0 < 8; k0++) B[k0] = *(const v8s*)(bb + k0 * 512);
                #pragma unroll
                for (int k0 = 0; k0 < 8; k0++) {
                    acc[nt][0] = __builtin_amdgcn_mfma_f32_16x16x32_bf16(A0[k0], B[k0], acc[nt][0], 0, 0, 0);
                    acc[nt][1] = __builtin_amdgcn_mfma_f32_16x16x32_bf16(A1[k0], B[k0], acc[nt][1], 0, 0, 0);
                    acc[nt][2] = __builtin_amdgcn_mfma_f32_16x16x32_bf16(A2[k0], B[k0], acc[nt][2], 0, 0, 0);
                }
            }
        }
        __syncthreads();

        #pragma unroll
        for (int nt = 0; nt < 4; nt++) {
            int col = w * 64 + nt * 16 + ln;
            float bias = ldf(fc3_b, col, bf);
            #pragma unroll
            for (int r = 0; r < 4; r++) {
                s3[(q * 4 + r) * 264 + col]      = f2s(lrelu(acc[nt][0][r] + bias));
                s3[(16 + q * 4 + r) * 264 + col] = f2s(lrelu(acc[nt][1][r] + bias));
                s3[(32 + q * 4 + r) * 264 + col] = f2s(lrelu(acc[nt][2][r] + bias));
            }
        }
    }
    __syncthreads();

    {
        int vi = t >> 2, l = t & 3;
        if (vi < MTV) {
            float p0 = 0.f, p1 = 0.f, p2 = 0.f;
            for (int k = l * 8; k < 256; k += 32) {
                #pragma unroll
                for (int j = 0; j < 8; j++) {
                    float a = s2f(s3[vi * 264 + k + j]);
                    p0 += a * s2f(sW4[0 * 256 + k + j]);
                    p1 += a * s2f(sW4[1 * 256 + k + j]);
                    p2 += a * s2f(sW4[2 * 256 + k + j]);
                }
            }
            #pragma unroll
            for (int s = 2; s; s >>= 1) {
                p0 += __shfl_down(p0, s, 4);
                p1 += __shfl_down(p1, s, 4);
                p2 += __shfl_down(p2, s, 4);
            }
            if (l == 0) {
                int vert = perm ? perm[base + vi] : (base + vi);
                float vx = ldf(v, vert * 3 + 0, bf);
                float vy = ldf(v, vert * 3 + 1, bf);
                float vz = ldf(v, vert * 3 + 2, bf);
                float o0 = vx + 0.1f * tanhf(p0 + ldf(fc4_b, 0, bf));
                float o1 = vy + 0.1f * tanhf(p1 + ldf(fc4_b, 1, bf));
                float o2 = vz + 0.1f * tanhf(p2 + ldf(fc4_b, 2, bf));
                if (bf) {
                    short* ob = (short*)out;
                    ob[vert * 3 + 0] = f2s(o0);
                    ob[vert * 3 + 1] = f2s(o1);
                    ob[vert * 3 + 2] = f2s(o2);
                } else {
                    float* of = (float*)out;
                    of[vert * 3 + 0] = o0;
                    of[vert * 3 + 1] = o1;
                    of[vert * 3 + 2] = o2;
                }
            }
        }
    }
}

// ================= SMALL-WS FALLBACK: R10 monolith =================
__global__ __launch_bounds__(256, 3) void fused_mfma_kernel(
    const void* __restrict__ v,
    const float* __restrict__ n_accum,
    const void* __restrict__ volume,
    const short* __restrict__ vol1,
    const short* __restrict__ vol2,
    const short* __restrict__ Wcomb,
    const float* __restrict__ bcomb,
    const short* __restrict__ fc2T,
    const short* __restrict__ fc3T,
    const void* __restrict__ fc1_w, const void* __restrict__ fc1_b,
    const void* __restrict__ fc2_b, const void* __restrict__ fc3_b,
    const void* __restrict__ fc4_w, const void* __restrict__ fc4_b,
    void* __restrict__ out,
    const int* __restrict__ flag)
{
    __shared__ __align__(16) char smem[51712];
    short* sX    = (short*)smem;
    short* sCube = (short*)(smem + 16896);
    short* sH    = (short*)(smem + 16896);
    short* s3    = (short*)smem;
    short* sW4   = (short*)(smem + 50176);

    const int bf = *flag;
    const int t = threadIdx.x;
    const int base = blockIdx.x * TVB;
    const int w = t >> 6, L = t & 63, q = L >> 4, ln = L & 15;
    const int laneoff = (q * 16 + ln) * 8;

    for (int idx = t; idx < TVB * 75; idx += 256) {
        int vl  = idx / 75;
        int r75 = idx - vl * 75;
        int n   = r75 / 25;
        int dd  = r75 - n * 25;
        int di  = dd / 5, dj = dd - di * 5;
        int vert = base + vl;
        short* dst = &sCube[vl * 392 + n * 125 + dd * 5];
        if (vert < NVERT) {
            float vx = ldf(v, vert * 3 + 0, bf);
            float vy = ldf(v, vert * 3 + 1, bf);
            float vz = ldf(v, vert * 3 + 2, bf);
            float scl = (n == 0) ? 96.0f : (n == 1 ? 48.0f : 24.0f);
            int lim = (LVOL >> n) - 3;
            int cx = (int)rintf((vx + 1.0f) * scl);
            int cy = (int)rintf((vy + 1.0f) * scl);
            int cz = (int)rintf((vz + 1.0f) * scl);
            cx = min(max(cx, 2), lim) + di - 2;
            cy = min(max(cy, 2), lim) + dj - 2;
            cz = min(max(cz, 2), lim);
            if (n == 0) {
                int b0 = (cx * LVOL + cy) * LVOL + (cz - 2);
                if (bf) {
                    const short* vp = (const short*)volume;
                    #pragma unroll
                    for (int i = 0; i < 5; i++) dst[i] = vp[b0 + i];
                } else {
                    const float* vp = (const float*)volume;
                    #pragma unroll
                    for (int i = 0; i < 5; i++) dst[i] = f2s(vp[b0 + i]);
                }
            } else {
                const short* lvl = (n == 1) ? vol1 : vol2;
                int dim = (n == 1) ? 96 : 48;
                int b0 = (cx * dim + cy) * dim + (cz - 2);
                #pragma unroll
                for (int i = 0; i < 5; i++) dst[i] = lvl[b0 + i];
            }
        } else {
            #pragma unroll
            for (int i = 0; i < 5; i++) dst[i] = 0;
        }
    }
    for (int idx = t; idx < TVB * 9; idx += 256) {
        int vl = idx / 9, rr = idx - vl * 9;
        sCube[vl * 392 + 375 + rr] = 0;
    }
    for (int i = t; i < 768; i += 256) {
        int j = i >> 8, k = i & 255;
        sW4[i] = f2s(ldf(fc4_w, k * 3 + j, bf));
    }
    {
        int vi = t & 31, cb = (t >> 5) * 16;
        int vert = base + vi;
        float i0 = 0.f, i1 = 0.f, i2 = 0.f, i3 = 0.f, i4 = 0.f, i5 = 0.f;
        if (vert < NVERT) {
            i0 = ldf(v, vert * 3 + 0, bf);
            i1 = ldf(v, vert * 3 + 1, bf);
            i2 = ldf(v, vert * 3 + 2, bf);
            float nx = n_accum[vert * 3 + 0];
            float ny = n_accum[vert * 3 + 1];
            float nz = n_accum[vert * 3 + 2];
            float inv = 1.0f / fmaxf(sqrtf(nx * nx + ny * ny + nz * nz), 1e-12f);
            i3 = nx * inv; i4 = ny * inv; i5 = nz * inv;
        }
        #pragma unroll
        for (int i = 0; i < 16; i++) {
            int c = cb + i;
            float acc = ldf(fc1_b, c, bf)
                      + i0 * ldf(fc1_w, 0 * 128 + c, bf)
                      + i1 * ldf(fc1_w, 1 * 128 + c, bf)
                      + i2 * ldf(fc1_w, 2 * 128 + c, bf)
                      + i3 * ldf(fc1_w, 3 * 128 + c, bf)
                      + i4 * ldf(fc1_w, 4 * 128 + c, bf)
                      + i5 * ldf(fc1_w, 5 * 128 + c, bf);
            sX[vi * 264 + c] = f2s(lrelu(acc));
        }
    }
    __syncthreads();

    #pragma unroll
    for (int nt = 0; nt < 2; nt++) {
        int col = w * 32 + nt * 16 + ln;
        const short* wb = Wcomb + ((w * 2 + nt) * 12 * 64) * 8 + laneoff;
        v4f acc0 = {0.f, 0.f, 0.f, 0.f}, acc1 = {0.f, 0.f, 0.f, 0.f};
        #pragma unroll
        for (int k0 = 0; k0 < 12; k0++) {
            v8s b  = *(const v8s*)(wb + k0 * 512);
            v8s a0 = *(const v8s*)&sCube[ln * 392 + k0 * 32 + q * 8];
            v8s a1 = *(const v8s*)&sCube[(16 + ln) * 392 + k0 * 32 + q * 8];
            acc0 = __builtin_amdgcn_mfma_f32_16x16x32_bf16(a0, b, acc0, 0, 0, 0);
            acc1 = __builtin_amdgcn_mfma_f32_16x16x32_bf16(a1, b, acc1, 0, 0, 0);
        }
        float bias = bcomb[col];
        #pragma unroll
        for (int r = 0; r < 4; r++) {
            sX[(q * 4 + r) * 264 + 128 + col]      = f2s(acc0[r] + bias);
            sX[(16 + q * 4 + r) * 264 + 128 + col] = f2s(acc1[r] + bias);
        }
    }
    __syncthreads();

    {
        v8s a0[8], a1[8];
        #pragma unroll
        for (int k0 = 0; k0 < 8; k0++) {
            a0[k0] = *(const v8s*)&sX[ln * 264 + k0 * 32 + q * 8];
            a1[k0] = *(const v8s*)&sX[(16 + ln) * 264 + k0 * 32 + q * 8];
        }
        #pragma unroll
        for (int nt = 0; nt < 8; nt++) {
            int col = w * 128 + nt * 16 + ln;
            const short* bb = fc2T + (w * 8 + nt) * 8 * 512 + laneoff;
            v4f acc0 = {0.f, 0.f, 0.f, 0.f}, acc1 = {0.f, 0.f, 0.f, 0.f};
            #pragma unroll
            for (int k0 = 0; k0 < 8; k0++) {
                v8s b = *(const v8s*)(bb + k0 * 512);
                acc0 = __builtin_amdgcn_mfma_f32_16x16x32_bf16(a0[k0], b, acc0, 0, 0, 0);
                acc1 = __builtin_amdgcn_mfma_f32_16x16x32_bf16(a1[k0], b, acc1, 0, 0, 0);
            }
            float bias = ldf(fc2_b, col, bf);
            #pragma unroll
            for (int r = 0; r < 4; r++) {
                sH[(q * 4 + r) * 520 + col]      = f2s(lrelu(acc0[r] + bias));
                sH[(16 + q * 4 + r) * 520 + col] = f2s(lrelu(acc1[r] + bias));
            }
        }
    }
    __syncthreads();

    {
        #pragma unroll
        for (int nt = 0; nt < 4; nt++) {
            int col = w * 64 + nt * 16 + ln;
            v4f acc0 = {0.f, 0.f, 0.f, 0.f}, acc1 = {0.f, 0.f, 0.f, 0.f};
            #pragma unroll
            for (int half = 0; half < 2; half++) {
                const short* bb = fc3T + ((w * 4 + nt) * 16 + half * 8) * 512 + laneoff;
                #pragma unroll
                for (int k0 = 0; k0 < 8; k0++) {
                    v8s b  = *(const v8s*)(bb + k0 * 512);
                    v8s a0 = *(const v8s*)&sH[ln * 520 + half * 256 + k0 * 32 + q * 8];
                    v8s a1 = *(const v8s*)&sH[(16 + ln) * 520 + half * 256 + k0 * 32 + q * 8];
                    acc0 = __builtin_amdgcn_mfma_f32_16x16x32_bf16(a0, b, acc0, 0, 0, 0);
                    acc1 = __builtin_amdgcn_mfma_f32_16x16x32_bf16(a1, b, acc1, 0, 0, 0);
                }
            }
            float bias = ldf(fc3_b, col, bf);
            #pragma unroll
            for (int r = 0; r < 4; r++) {
                s3[(q * 4 + r) * 264 + col]      = f2s(lrelu(acc0[r] + bias));
                s3[(16 + q * 4 + r) * 264 + col] = f2s(lrelu(acc1[r] + bias));
            }
        }
    }
    __syncthreads();

    {
        int vi = t >> 3, l = t & 7;
        float p0 = 0.f, p1 = 0.f, p2 = 0.f;
        for (int k = l; k < 256; k += 8) {
            float a = s2f(s3[vi * 264 + k]);
            p0 += a * s2f(sW4[0 * 256 + k]);
            p1 += a * s2f(sW4[1 * 256 + k]);
            p2 += a * s2f(sW4[2 * 256 + k]);
        }
        #pragma unroll
        for (int s = 4; s; s >>= 1) {
            p0 += __shfl_down(p0, s, 8);
            p1 += __shfl_down(p1, s, 8);
            p2 += __shfl_down(p2, s, 8);
        }
        if (l == 0) {
            int vert = base + vi;
            if (vert < NVERT) {
                float vx = ldf(v, vert * 3 + 0, bf);
                float vy = ldf(v, vert * 3 + 1, bf);
                float vz = ldf(v, vert * 3 + 2, bf);
                float o0 = vx + 0.1f * tanhf(p0 + ldf(fc4_b, 0, bf));
                float o1 = vy + 0.1f * tanhf(p1 + ldf(fc4_b, 1, bf));
                float o2 = vz + 0.1f * tanhf(p2 + ldf(fc4_b, 2, bf));
                if (bf) {
                    short* ob = (short*)out;
                    ob[vert * 3 + 0] = f2s(o0);
                    ob[vert * 3 + 1] = f2s(o1);
                    ob[vert * 3 + 2] = f2s(o2);
                } else {
                    float* of = (float*)out;
                    of[vert * 3 + 0] = o0;
                    of[vert * 3 + 1] = o1;
                    of[vert * 3 + 2] = o2;
                }
            }
        }
    }
}

extern "C" void kernel_launch(void* const* d_in, const int* in_sizes, int n_in,
                              void* d_out, int out_size, void* d_ws, size_t ws_size,
                              hipStream_t stream) {
    const void* v      = d_in[0];
    const int*  f      = (const int*)d_in[1];
    const void* volume = d_in[2];
    const void* fc1_w  = d_in[3];
    const void* fc1_b  = d_in[4];
    const void* fc2_w  = d_in[5];
    const void* fc2_b  = d_in[6];
    const void* fc3_w  = d_in[7];
    const void* fc3_b  = d_in[8];
    const void* fc4_w  = d_in[9];
    const void* fc4_b  = d_in[10];
    const void* conv_w = d_in[11];
    const void* conv_b = d_in[12];
    const void* lfc_w  = d_in[13];
    const void* lfc_b  = d_in[14];

    char* wsb = (char*)d_ws;
    const int big  = (ws_size >= WS_BIG_NEED) ? 1 : 0;
    const int b16  = (ws_size >= WS_B16_NEED) ? 1 : 0;
    const int srt  = (ws_size >= WS_SORT_NEED) ? 1 : 0;

    if (big) {
        int*   flag    = (int*)wsb;
        float* n_accum = (float*)(wsb + 64);
        short* vol1b   = (short*)(wsb + 1800064);   // 96^3 bf16
        short* vol2b   = (short*)(wsb + 5339008);   // 48^3 bf16
        short* Wcomb8  = (short*)(wsb + 5560192);   // 128 x 608 bf16 (155,648 B, fits gap)
        short* Wcomb   = (short*)(wsb + 5781376);   // 128 x 384 bf16 (legacy K=384)
        float* bcomb   = (float*)(wsb + 5879680);
        short* fc2T    = (short*)(wsb + 5880192);
        short* fc3T    = (short*)(wsb + 6142336);
        short* xloc    = (short*)(wsb + 6404480);
        short* vol0b   = b16 ? (short*)(wsb + 44808576) : nullptr;
        int*   hist    = srt ? (int*)(wsb + 58964352) : nullptr;
        int*   keys    = srt ? (int*)(wsb + 59019648) : nullptr;
        int*   perm    = srt ? (int*)(wsb + 59619648) : nullptr;

        hipMemsetAsync(n_accum, 0, NVERT * 3 * sizeof(float), stream);
        detect_kernel<<<1, 256, 0, stream>>>(v, flag);
        if (srt) {
            hipMemsetAsync(hist, 0, NBUCKET * sizeof(int), stream);
            sort_hist_kernel<<<(NVERT + 255) / 256, 256, 0, stream>>>(v, hist, keys, flag);
            sort_scan_kernel<<<1, 1024, 0, stream>>>(hist);
            sort_scatter_kernel<<<(NVERT + 255) / 256, 256, 0, stream>>>(hist, keys, perm);
        }
        mega_prep2_kernel<<<P2_CP0_START + (b16 ? P2_CP0 : 0), 256, 0, stream>>>(
            volume, vol1b, vol2b,
            conv_w, lfc_w, conv_b, lfc_b, Wcomb, Wcomb8, bcomb, flag, vol0b);
        int ngather = (NVERT + TVB - 1) / TVB;
        if (srt) {
            gather8_kernel<<<ngather + NB_NORM + NB_TRS, 256, 0, stream>>>(
                v, f, n_accum, volume, vol1b, vol2b, vol0b, perm, Wcomb8, bcomb,
                fc2_w, fc3_w, fc2T, fc3T, xloc, flag, ngather);
        } else {
            gather_ext_kernel<<<ngather + NB_NORM + NB_TRS, 256, 0, stream>>>(
                v, f, n_accum, volume, vol1b, vol2b, vol0b, nullptr, Wcomb, bcomb,
                fc2_w, fc3_w, fc2T, fc3T, xloc, flag, ngather);
        }
        mlp_kernel<<<(NVERT + MTV - 1) / MTV, 256, 0, stream>>>(
            v, n_accum, xloc, perm, fc2T, fc3T,
            fc1_w, fc1_b, fc2_b, fc3_b, fc4_w, fc4_b, d_out, flag);
    } else {
        int*   flag    = (int*)wsb;
        float* n_accum = (float*)(wsb + 64);
        short* vol1    = (short*)(wsb + 1800064);
        short* vol2    = (short*)(wsb + 3569536);
        short* Wcomb   = (short*)(wsb + 3790720);
        float* bcomb   = (float*)(wsb + 3889024);
        short* fc2T    = (short*)(wsb + 3889536);
        short* fc3T    = (short*)(wsb + 4151680);

        hipMemsetAsync(n_accum, 0, NVERT * 3 * sizeof(float), stream);
        detect_kernel<<<1, 256, 0, stream>>>(v, flag);
        mega_prep2_kernel<<<P2_WC8_START, 256, 0, stream>>>(
            volume, vol1, vol2,
            conv_w, lfc_w, conv_b, lfc_b, Wcomb, nullptr, bcomb, flag, nullptr);
        gather_ext_kernel<<<NB_NORM + NB_TRS, 256, 0, stream>>>(
            v, f, n_accum, volume, vol1, vol2, nullptr, nullptr, Wcomb, bcomb,
            fc2_w, fc3_w, fc2T, fc3T, nullptr, flag, 0);
        fused_mfma_kernel<<<(NVERT + TVB - 1) / TVB, 256, 0, stream>>>(
            v, n_accum, volume, vol1, vol2, Wcomb, bcomb, fc2T, fc3T,
            fc1_w, fc1_b, fc2_b, fc3_b, fc4_w, fc4_b, d_out, flag);
    }
}

// Round 13
// 528.194 us; speedup vs baseline: 1.0530x; 1.0424x over previous
//
#include <hip/hip_runtime.h>
#include <hip/hip_bf16.h>
#include <math.h>

#define NVERT 150000
#define NFACE 300000
#define LVOL  192
#define TVB   32
#define MTV   48      // vertices per block in mlp kernel (M = 3 MFMA rows)

// mega_prep2 block-range partition
#define P2_POOL1 3456
#define P2_POOL2 432
#define P2_WC    193
#define P2_WC8   304
#define P2_CP0   3456
#define P2_POOL2_START (P2_POOL1)
#define P2_WC_START    (P2_POOL1 + P2_POOL2)
#define P2_WC8_START   (P2_WC_START + P2_WC)
#define P2_CP0_START   (P2_WC8_START + P2_WC8)

// extra blocks appended to gather grid (mlp-only prerequisites)
#define NB_NORM 1172
#define NB_TRS  1024

#define NBUCKET 13824     // 24^3 cells of 8^3 voxels
#define WS_BIG_NEED  44808576ull
#define WS_B16_NEED  58964352ull   // + vol0b (192^3 bf16)
#define WS_SORT_NEED 62619648ull   // + hist + keys + perm + rank + vperm(f32x3)

typedef short v8s __attribute__((ext_vector_type(8)));
typedef float v4f __attribute__((ext_vector_type(4)));
typedef unsigned int v4u __attribute__((ext_vector_type(4)));

__device__ __forceinline__ float s2f(short s) {
    unsigned int u = ((unsigned int)(unsigned short)s) << 16;
    return __builtin_bit_cast(float, u);
}
__device__ __forceinline__ short f2s(float f) {
    __hip_bfloat16 h = __float2bfloat16(f);
    return __builtin_bit_cast(short, h);
}
__device__ __forceinline__ float lrelu(float x) { return x > 0.f ? x : 0.15f * x; }

__device__ __forceinline__ float ldf(const void* __restrict__ p, int i, int bf) {
    return bf ? s2f(((const short*)p)[i]) : ((const float*)p)[i];
}

// Banked H addressing (shorts): col c in [0,512), row r in [0,48).
__device__ __forceinline__ int haddr(int r, int c) {
    int hi  = c >> 7;
    int mid = (c >> 4) & 7;
    int lo  = c & 15;
    int wc  = hi * 64 + (mid & 3) * 16 + lo;
    return ((mid < 4) ? 0 : 12672) + r * 264 + wc;
}

// ---- detect input dtype (bf16 vs fp32) ----
__global__ void detect_kernel(const void* __restrict__ v, int* __restrict__ flag) {
    __shared__ int s_ok;
    int t = threadIdx.x;
    if (t == 0) s_ok = 1;
    __syncthreads();
    float x = s2f(((const short*)v)[t]);
    if (!(fabsf(x) <= 1.0f)) atomicAnd(&s_ok, 0);
    __syncthreads();
    if (t == 0) *flag = s_ok;
}

// ---- spatial counting sort (3 kernels) ----
// scatter also emits rank (inverse perm) and vperm (slot-ordered f32 coords)
// so mlp's v/n_accum accesses become LINEAR (R11/R12: perm-tax on mlp was
// +23 us: FETCH 23.7->38 MB from scattered v/n_accum reads).
__global__ __launch_bounds__(256) void sort_hist_kernel(
    const void* __restrict__ v, int* __restrict__ hist, int* __restrict__ keys,
    const int* __restrict__ flag)
{
    const int bf = *flag;
    int vert = blockIdx.x * 256 + threadIdx.x;
    if (vert >= NVERT) return;
    float vx = ldf(v, vert * 3 + 0, bf);
    float vy = ldf(v, vert * 3 + 1, bf);
    float vz = ldf(v, vert * 3 + 2, bf);
    int cx = min(max((int)rintf((vx + 1.0f) * 96.0f), 2), 189);
    int cy = min(max((int)rintf((vy + 1.0f) * 96.0f), 2), 189);
    int cz = min(max((int)rintf((vz + 1.0f) * 96.0f), 2), 189);
    int key = ((cx >> 3) * 24 + (cy >> 3)) * 24 + (cz >> 3);
    keys[vert] = key;
    atomicAdd(&hist[key], 1);
}

__global__ __launch_bounds__(1024) void sort_scan_kernel(int* __restrict__ hist)
{
    __shared__ int partial[1024];
    const int t = threadIdx.x;
    const int CH = 14;
    int base = t * CH;
    int sum = 0;
    #pragma unroll
    for (int i = 0; i < CH; i++) {
        int idx = base + i;
        if (idx < NBUCKET) sum += hist[idx];
    }
    partial[t] = sum;
    __syncthreads();
    for (int off = 1; off < 1024; off <<= 1) {
        int x = (t >= off) ? partial[t - off] : 0;
        __syncthreads();
        partial[t] += x;
        __syncthreads();
    }
    int run = partial[t] - sum;
    for (int i = 0; i < CH; i++) {
        int idx = base + i;
        if (idx < NBUCKET) {
            int c = hist[idx];
            hist[idx] = run;
            run += c;
        }
    }
}

__global__ __launch_bounds__(256) void sort_scatter_kernel(
    const void* __restrict__ v,
    int* __restrict__ cursor, const int* __restrict__ keys,
    int* __restrict__ perm, int* __restrict__ rank, float* __restrict__ vperm,
    const int* __restrict__ flag)
{
    const int bf = *flag;
    int vert = blockIdx.x * 256 + threadIdx.x;
    if (vert >= NVERT) return;
    int pos = atomicAdd(&cursor[keys[vert]], 1);
    perm[pos] = vert;
    rank[vert] = pos;
    vperm[pos * 3 + 0] = ldf(v, vert * 3 + 0, bf);
    vperm[pos * 3 + 1] = ldf(v, vert * 3 + 1, bf);
    vperm[pos * 3 + 2] = ldf(v, vert * 3 + 2, bf);
}

// ---------------- mega_prep2: pools | Wcomb384 | Wcomb8(K=608) | [vol0b] ----
__global__ __launch_bounds__(256) void mega_prep2_kernel(
    const void* __restrict__ volume,
    short* __restrict__ vol1b, short* __restrict__ vol2b,
    const void* __restrict__ conv_w, const void* __restrict__ lfc_w,
    const void* __restrict__ conv_b, const void* __restrict__ lfc_b,
    short* __restrict__ Wcomb, short* __restrict__ Wcomb8, float* __restrict__ bcomb,
    const int* __restrict__ flag,
    short* __restrict__ vol0b)
{
    const int bf = *flag;
    const int bid = blockIdx.x;
    const int t = threadIdx.x;

    if (bid < P2_POOL1) {
        int id = bid * 256 + t;
        int z = id % 96, y = (id / 96) % 96, x = id / (96 * 96);
        float s = 0.f;
        #pragma unroll
        for (int a = 0; a < 2; a++)
            #pragma unroll
            for (int b = 0; b < 2; b++)
                #pragma unroll
                for (int c = 0; c < 2; c++)
                    s += ldf(volume, (2 * x + a) * (LVOL * LVOL) + (2 * y + b) * LVOL + (2 * z + c), bf);
        s *= 0.125f;
        vol1b[id] = f2s(s);
    } else if (bid < P2_WC_START) {
        int id = (bid - P2_POOL2_START) * 256 + t;
        int z = id % 48, y = (id / 48) % 48, x = id / (48 * 48);
        float s = 0.f;
        for (int a = 0; a < 4; a++)
            for (int b = 0; b < 4; b++)
                #pragma unroll
                for (int c = 0; c < 4; c++)
                    s += ldf(volume, (4 * x + a) * (LVOL * LVOL) + (4 * y + b) * LVOL + (4 * z + c), bf);
        s *= 0.015625f;
        vol2b[id] = f2s(s);
    } else if (bid < P2_WC8_START) {
        int id = (bid - P2_WC_START) * 256 + t;
        if (id < 49152) {
            int j = id / 384, k = id - j * 384;
            float acc = 0.f;
            if (k < 375) {
                float a0 = 0.f, a1 = 0.f, a2 = 0.f, a3 = 0.f;
                for (int o = 0; o < 128; o += 4) {
                    a0 += ldf(conv_w, (o + 0) * 375 + k, bf) * ldf(lfc_w, (o + 0) * 128 + j, bf);
                    a1 += ldf(conv_w, (o + 1) * 375 + k, bf) * ldf(lfc_w, (o + 1) * 128 + j, bf);
                    a2 += ldf(conv_w, (o + 2) * 375 + k, bf) * ldf(lfc_w, (o + 2) * 128 + j, bf);
                    a3 += ldf(conv_w, (o + 3) * 375 + k, bf) * ldf(lfc_w, (o + 3) * 128 + j, bf);
                }
                acc = (a0 + a1) + (a2 + a3);
            }
            int tile = j >> 4, ln = j & 15;
            int kk = k >> 5, r = k & 31, qq = r >> 3, e = r & 7;
            Wcomb[((tile * 12 + kk) * 64 + qq * 16 + ln) * 8 + e] = f2s(acc);
        } else if (id < 49152 + 128) {
            int j = id - 49152;
            float acc = ldf(lfc_b, j, bf);
            for (int o = 0; o < 128; o++) acc += ldf(conv_b, o, bf) * ldf(lfc_w, o * 128 + j, bf);
            bcomb[j] = acc;
        }
    } else if (bid < P2_CP0_START) {
        int id = (bid - P2_WC8_START) * 256 + t;    // 304*256 = 77824 exactly
        int j = id / 608, k = id - j * 608;
        int r = k >> 3, e = k & 7;
        float acc = 0.f;
        if (e < 5 && r < 75) {
            int k375 = (r / 25) * 125 + (r % 25) * 5 + e;
            float a0 = 0.f, a1 = 0.f, a2 = 0.f, a3 = 0.f;
            for (int o = 0; o < 128; o += 4) {
                a0 += ldf(conv_w, (o + 0) * 375 + k375, bf) * ldf(lfc_w, (o + 0) * 128 + j, bf);
                a1 += ldf(conv_w, (o + 1) * 375 + k375, bf) * ldf(lfc_w, (o + 1) * 128 + j, bf);
                a2 += ldf(conv_w, (o + 2) * 375 + k375, bf) * ldf(lfc_w, (o + 2) * 128 + j, bf);
                a3 += ldf(conv_w, (o + 3) * 375 + k375, bf) * ldf(lfc_w, (o + 3) * 128 + j, bf);
            }
            acc = (a0 + a1) + (a2 + a3);
        }
        int tile = j >> 4, ln = j & 15;
        int kk = k >> 5, rr = k & 31, qq = rr >> 3, ee = rr & 7;
        Wcomb8[((tile * 19 + kk) * 64 + qq * 16 + ln) * 8 + ee] = f2s(acc);
    } else {
        if (bf) return;
        int id = (bid - P2_CP0_START) * 2048 + t * 8;
        const float* vp = (const float*)volume;
        short tmp[8];
        #pragma unroll
        for (int i = 0; i < 8; i++) tmp[i] = f2s(vp[id + i]);
        *(v8s*)&vol0b[id] = *(v8s*)tmp;
    }
}

// ================= gather8: K=608 vectorized gather (srt path) =================
// Vertex coords read LINEARLY from vperm; normals accumulate into n_accum in
// SLOT order via rank; xloc written in slot order.
__global__ __launch_bounds__(256, 4) void gather8_kernel(
    const void* __restrict__ v,
    const int* __restrict__ f, float* __restrict__ n_accum,
    const void* __restrict__ volume,
    const short* __restrict__ vol1b,
    const short* __restrict__ vol2b,
    const short* __restrict__ vol0b,
    const float* __restrict__ vperm,
    const int* __restrict__ rank,
    const short* __restrict__ Wcomb8,
    const float* __restrict__ bcomb,
    const void* __restrict__ fc2_w, const void* __restrict__ fc3_w,
    short* __restrict__ fc2T, short* __restrict__ fc3T,
    short* __restrict__ xloc,
    const int* __restrict__ flag, int ngather)
{
    __shared__ __align__(16) short sCube[TVB * 608];   // 38,912 B
    __shared__ int sIdx[TVB * 4];

    const int bf = *flag;
    const int t = threadIdx.x;
    const int bid = blockIdx.x;

    if (bid >= ngather) {
        int rb = bid - ngather;
        if (rb < NB_NORM) {
            int ft = rb * 256 + t;
            if (ft >= NFACE) return;
            int i0 = f[ft * 3 + 0], i1 = f[ft * 3 + 1], i2 = f[ft * 3 + 2];
            float p0x = ldf(v, i0 * 3 + 0, bf), p0y = ldf(v, i0 * 3 + 1, bf), p0z = ldf(v, i0 * 3 + 2, bf);
            float p1x = ldf(v, i1 * 3 + 0, bf), p1y = ldf(v, i1 * 3 + 1, bf), p1z = ldf(v, i1 * 3 + 2, bf);
            float p2x = ldf(v, i2 * 3 + 0, bf), p2y = ldf(v, i2 * 3 + 1, bf), p2z = ldf(v, i2 * 3 + 2, bf);
            float e1x = p1x - p0x, e1y = p1y - p0y, e1z = p1z - p0z;
            float e2x = p2x - p0x, e2y = p2y - p0y, e2z = p2z - p0z;
            float cx = e1y * e2z - e1z * e2y;
            float cy = e1z * e2x - e1x * e2z;
            float cz = e1x * e2y - e1y * e2x;
            int s0 = rank[i0], s1 = rank[i1], s2 = rank[i2];   // slot-ordered n_accum
            atomicAdd(&n_accum[s0 * 3 + 0], cx); atomicAdd(&n_accum[s0 * 3 + 1], cy); atomicAdd(&n_accum[s0 * 3 + 2], cz);
            atomicAdd(&n_accum[s1 * 3 + 0], cx); atomicAdd(&n_accum[s1 * 3 + 1], cy); atomicAdd(&n_accum[s1 * 3 + 2], cz);
            atomicAdd(&n_accum[s2 * 3 + 0], cx); atomicAdd(&n_accum[s2 * 3 + 1], cy); atomicAdd(&n_accum[s2 * 3 + 2], cz);
        } else {
            int id = (rb - NB_NORM) * 256 + t;
            if (id < 131072) {
                int col = id >> 8, k = id & 255;
                int tile = col >> 4, ln = col & 15;
                int kk = k >> 5, r = k & 31, qq = r >> 3, e = r & 7;
                fc2T[((tile * 8 + kk) * 64 + qq * 16 + ln) * 8 + e] = f2s(ldf(fc2_w, k * 512 + col, bf));
            } else {
                int i = id - 131072;
                int col = i >> 9, k = i & 511;
                int tile = col >> 4, ln = col & 15;
                int kk = k >> 5, r = k & 31, qq = r >> 3, e = r & 7;
                fc3T[((tile * 16 + kk) * 64 + qq * 16 + ln) * 8 + e] = f2s(ldf(fc3_w, k * 256 + col, bf));
            }
        }
        return;
    }

    const int base = bid * TVB;
    const int w = t >> 6, L = t & 63, q = L >> 4, ln = L & 15;
    const short* v0 = bf ? (const short*)volume : vol0b;

    if (t < TVB) {
        int slot = min(base + t, NVERT - 1);
        float vx = vperm[slot * 3 + 0];
        float vy = vperm[slot * 3 + 1];
        float vz = vperm[slot * 3 + 2];
        #pragma unroll
        for (int n = 0; n < 3; n++) {
            float scl = (n == 0) ? 96.0f : (n == 1 ? 48.0f : 24.0f);
            int dim = LVOL >> n, lim = dim - 3;
            int cx = min(max((int)rintf((vx + 1.0f) * scl), 2), lim);
            int cy = min(max((int)rintf((vy + 1.0f) * scl), 2), lim);
            int cz = min(max((int)rintf((vz + 1.0f) * scl), 2), lim);
            sIdx[t * 4 + n] = (cx * dim + cy) * dim + (cz - 2);
        }
        // zero tail rows k=600..607 for this vertex
        *(v4u*)&sCube[t * 608 + 600] = (v4u){0u, 0u, 0u, 0u};
    }
    __syncthreads();

    for (int idx = t; idx < TVB * 75; idx += 256) {
        int n   = idx / 800;
        int rem = idx - n * 800;
        int vl  = rem / 25;
        int dd  = rem - vl * 25;
        int di  = dd / 5, dj = dd - di * 5;
        int dim = LVOL >> n;
        int addr = sIdx[vl * 4 + n] + (di - 2) * dim * dim + (dj - 2) * dim;
        int r = n * 25 + dd;
        if (n == 0 && bf) {
            const short* vp = (const short*)volume;
            short* dst = &sCube[vl * 608 + r * 8];
            #pragma unroll
            for (int i = 0; i < 5; i++) dst[i] = vp[addr + i];
            dst[5] = 0; dst[6] = 0; dst[7] = 0;
        } else {
            const short* lvl = (n == 0) ? v0 : (n == 1 ? vol1b : vol2b);
            int p  = addr & 1;
            int a0 = addr - p;
            const unsigned int* u = (const unsigned int*)(lvl + a0);
            unsigned int x0 = u[0], x1 = u[1], x2 = u[2];
            unsigned int d0, d1, d2;
            if (p) {
                d0 = (x0 >> 16) | (x1 << 16);
                d1 = (x1 >> 16) | (x2 << 16);
                d2 = (x2 >> 16);
            } else {
                d0 = x0;
                d1 = x1;
                d2 = x2 & 0xFFFFu;
            }
            *(v4u*)&sCube[vl * 608 + r * 8] = (v4u){d0, d1, d2, 0u};
        }
    }
    __syncthreads();

    #pragma unroll
    for (int nt = 0; nt < 2; nt++) {
        int col = w * 32 + nt * 16 + ln;
        const short* wb = Wcomb8 + ((w * 2 + nt) * 19 * 64 + q * 16 + ln) * 8;
        v4f acc0 = {0.f, 0.f, 0.f, 0.f}, acc1 = {0.f, 0.f, 0.f, 0.f};
        #pragma unroll
        for (int k0 = 0; k0 < 19; k0++) {
            v8s b  = *(const v8s*)(wb + k0 * 512);
            v8s a0 = *(const v8s*)&sCube[ln * 608 + k0 * 32 + q * 8];
            v8s a1 = *(const v8s*)&sCube[(16 + ln) * 608 + k0 * 32 + q * 8];
            acc0 = __builtin_amdgcn_mfma_f32_16x16x32_bf16(a0, b, acc0, 0, 0, 0);
            acc1 = __builtin_amdgcn_mfma_f32_16x16x32_bf16(a1, b, acc1, 0, 0, 0);
        }
        float bias = bcomb[col];
        #pragma unroll
        for (int r = 0; r < 4; r++) {
            xloc[(base + q * 4 + r) * 128 + col]      = f2s(acc0[r] + bias);
            xloc[(base + 16 + q * 4 + r) * 128 + col] = f2s(acc1[r] + bias);
        }
    }
}

// ================= gather_ext (K=384): fallback when sort workspace absent ======
__global__ __launch_bounds__(256, 6) void gather_ext_kernel(
    const void* __restrict__ v,
    const int* __restrict__ f, float* __restrict__ n_accum,
    const void* __restrict__ volume,
    const short* __restrict__ vol1b,
    const short* __restrict__ vol2b,
    const short* __restrict__ vol0b,
    const short* __restrict__ Wcomb,
    const float* __restrict__ bcomb,
    const void* __restrict__ fc2_w, const void* __restrict__ fc3_w,
    short* __restrict__ fc2T, short* __restrict__ fc3T,
    short* __restrict__ xloc,
    const int* __restrict__ flag, int ngather)
{
    __shared__ __align__(16) short sCube[TVB * 392];
    __shared__ int sIdx[TVB * 4];

    const int bf = *flag;
    const int t = threadIdx.x;
    const int bid = blockIdx.x;

    if (bid >= ngather) {
        int rb = bid - ngather;
        if (rb < NB_NORM) {
            int ft = rb * 256 + t;
            if (ft >= NFACE) return;
            int i0 = f[ft * 3 + 0], i1 = f[ft * 3 + 1], i2 = f[ft * 3 + 2];
            float p0x = ldf(v, i0 * 3 + 0, bf), p0y = ldf(v, i0 * 3 + 1, bf), p0z = ldf(v, i0 * 3 + 2, bf);
            float p1x = ldf(v, i1 * 3 + 0, bf), p1y = ldf(v, i1 * 3 + 1, bf), p1z = ldf(v, i1 * 3 + 2, bf);
            float p2x = ldf(v, i2 * 3 + 0, bf), p2y = ldf(v, i2 * 3 + 1, bf), p2z = ldf(v, i2 * 3 + 2, bf);
            float e1x = p1x - p0x, e1y = p1y - p0y, e1z = p1z - p0z;
            float e2x = p2x - p0x, e2y = p2y - p0y, e2z = p2z - p0z;
            float cx = e1y * e2z - e1z * e2y;
            float cy = e1z * e2x - e1x * e2z;
            float cz = e1x * e2y - e1y * e2x;
            atomicAdd(&n_accum[i0 * 3 + 0], cx); atomicAdd(&n_accum[i0 * 3 + 1], cy); atomicAdd(&n_accum[i0 * 3 + 2], cz);
            atomicAdd(&n_accum[i1 * 3 + 0], cx); atomicAdd(&n_accum[i1 * 3 + 1], cy); atomicAdd(&n_accum[i1 * 3 + 2], cz);
            atomicAdd(&n_accum[i2 * 3 + 0], cx); atomicAdd(&n_accum[i2 * 3 + 1], cy); atomicAdd(&n_accum[i2 * 3 + 2], cz);
        } else {
            int id = (rb - NB_NORM) * 256 + t;
            if (id < 131072) {
                int col = id >> 8, k = id & 255;
                int tile = col >> 4, ln = col & 15;
                int kk = k >> 5, r = k & 31, qq = r >> 3, e = r & 7;
                fc2T[((tile * 8 + kk) * 64 + qq * 16 + ln) * 8 + e] = f2s(ldf(fc2_w, k * 512 + col, bf));
            } else {
                int i = id - 131072;
                int col = i >> 9, k = i & 511;
                int tile = col >> 4, ln = col & 15;
                int kk = k >> 5, r = k & 31, qq = r >> 3, e = r & 7;
                fc3T[((tile * 16 + kk) * 64 + qq * 16 + ln) * 8 + e] = f2s(ldf(fc3_w, k * 256 + col, bf));
            }
        }
        return;
    }

    const int base = bid * TVB;
    const int w = t >> 6, L = t & 63, q = L >> 4, ln = L & 15;
    const short* v0 = bf ? (const short*)volume : vol0b;

    if (t < TVB) {
        int vert = min(base + t, NVERT - 1);
        float vx = ldf(v, vert * 3 + 0, bf);
        float vy = ldf(v, vert * 3 + 1, bf);
        float vz = ldf(v, vert * 3 + 2, bf);
        #pragma unroll
        for (int n = 0; n < 3; n++) {
            float scl = (n == 0) ? 96.0f : (n == 1 ? 48.0f : 24.0f);
            int dim = LVOL >> n, lim = dim - 3;
            int cx = min(max((int)rintf((vx + 1.0f) * scl), 2), lim);
            int cy = min(max((int)rintf((vy + 1.0f) * scl), 2), lim);
            int cz = min(max((int)rintf((vz + 1.0f) * scl), 2), lim);
            sIdx[t * 4 + n] = (cx * dim + cy) * dim + (cz - 2);
        }
    }
    __syncthreads();

    for (int idx = t; idx < TVB * 75; idx += 256) {
        int n   = idx / 800;
        int rem = idx - n * 800;
        int vl  = rem / 25;
        int dd  = rem - vl * 25;
        int di  = dd / 5, dj = dd - di * 5;
        int dim = LVOL >> n;
        int addr = sIdx[vl * 4 + n] + (di - 2) * dim * dim + (dj - 2) * dim;
        short* dst = &sCube[vl * 392 + n * 125 + dd * 5];
        if (n == 0 && v0 == nullptr) {
            const float* vp = (const float*)volume;
            #pragma unroll
            for (int i = 0; i < 5; i++) dst[i] = f2s(vp[addr + i]);
        } else {
            const short* lvl = (n == 0) ? v0 : (n == 1 ? vol1b : vol2b);
            #pragma unroll
            for (int i = 0; i < 5; i++) dst[i] = lvl[addr + i];
        }
    }
    for (int idx = t; idx < TVB * 9; idx += 256) {
        int vl = idx / 9, rr = idx - vl * 9;
        sCube[vl * 392 + 375 + rr] = 0;
    }
    __syncthreads();

    #pragma unroll
    for (int nt = 0; nt < 2; nt++) {
        int col = w * 32 + nt * 16 + ln;
        const short* wb = Wcomb + ((w * 2 + nt) * 12 * 64 + q * 16 + ln) * 8;
        v4f acc0 = {0.f, 0.f, 0.f, 0.f}, acc1 = {0.f, 0.f, 0.f, 0.f};
        #pragma unroll
        for (int k0 = 0; k0 < 12; k0++) {
            v8s b  = *(const v8s*)(wb + k0 * 512);
            v8s a0 = *(const v8s*)&sCube[ln * 392 + k0 * 32 + q * 8];
            v8s a1 = *(const v8s*)&sCube[(16 + ln) * 392 + k0 * 32 + q * 8];
            acc0 = __builtin_amdgcn_mfma_f32_16x16x32_bf16(a0, b, acc0, 0, 0, 0);
            acc1 = __builtin_amdgcn_mfma_f32_16x16x32_bf16(a1, b, acc1, 0, 0, 0);
        }
        float bias = bcomb[col];
        #pragma unroll
        for (int r = 0; r < 4; r++) {
            xloc[(base + q * 4 + r) * 128 + col]      = f2s(acc0[r] + bias);
            xloc[(base + 16 + q * 4 + r) * 128 + col] = f2s(acc1[r] + bias);
        }
    }
}

// ---- kernel B: MLP, 48 slots/block (M=3 MFMA rows) ----
// With sort: vperm (f32, slot-ordered) and n_accum (slot-ordered) read LINEARLY;
// only the final out[perm[slot]] write is scattered (~10 MB RMW).
__global__ __launch_bounds__(256, 3) void mlp_kernel(
    const void* __restrict__ v,
    const float* __restrict__ vperm,     // may be null (identity, read v)
    const float* __restrict__ n_accum,
    const short* __restrict__ xloc,
    const int* __restrict__ perm,        // may be null (identity)
    const short* __restrict__ fc2T,
    const short* __restrict__ fc3T,
    const void* __restrict__ fc1_w, const void* __restrict__ fc1_b,
    const void* __restrict__ fc2_b, const void* __restrict__ fc3_b,
    const void* __restrict__ fc4_w, const void* __restrict__ fc4_b,
    void* __restrict__ out,
    const int* __restrict__ flag)
{
    __shared__ __align__(16) char smem[52224];
    short* sX  = (short*)smem;
    short* sHB = (short*)smem;
    short* s3  = (short*)smem;
    short* sW4 = (short*)(smem + 50688);

    const int bf = *flag;
    const int t = threadIdx.x;
    const int base = blockIdx.x * MTV;
    const int w = t >> 6, L = t & 63, q = L >> 4, ln = L & 15;
    const int laneoff = (q * 16 + ln) * 8;

    for (int id = t; id < MTV * 16; id += 256) {
        int row = id >> 4, seg = id & 15;
        v8s x = *(const v8s*)(xloc + (base + row) * 128 + seg * 8);
        *(v8s*)&sX[row * 264 + 128 + seg * 8] = x;
    }

    for (int i = t; i < 768; i += 256) {
        int j = i >> 8, k = i & 255;
        sW4[i] = f2s(ldf(fc4_w, k * 3 + j, bf));
    }

    {
        int vi = t >> 2, cb = (t & 3) * 32;
        if (vi < MTV) {
            int slot = base + vi;
            float i0, i1, i2;
            if (vperm) {
                i0 = vperm[slot * 3 + 0];
                i1 = vperm[slot * 3 + 1];
                i2 = vperm[slot * 3 + 2];
            } else {
                i0 = ldf(v, slot * 3 + 0, bf);
                i1 = ldf(v, slot * 3 + 1, bf);
                i2 = ldf(v, slot * 3 + 2, bf);
            }
            float nx = n_accum[slot * 3 + 0];
            float ny = n_accum[slot * 3 + 1];
            float nz = n_accum[slot * 3 + 2];
            float inv = 1.0f / fmaxf(sqrtf(nx * nx + ny * ny + nz * nz), 1e-12f);
            float i3 = nx * inv, i4 = ny * inv, i5 = nz * inv;
            #pragma unroll 8
            for (int i = 0; i < 32; i++) {
                int c = cb + i;
                float acc = ldf(fc1_b, c, bf)
                          + i0 * ldf(fc1_w, 0 * 128 + c, bf)
                          + i1 * ldf(fc1_w, 1 * 128 + c, bf)
                          + i2 * ldf(fc1_w, 2 * 128 + c, bf)
                          + i3 * ldf(fc1_w, 3 * 128 + c, bf)
                          + i4 * ldf(fc1_w, 4 * 128 + c, bf)
                          + i5 * ldf(fc1_w, 5 * 128 + c, bf);
                sX[vi * 264 + c] = f2s(lrelu(acc));
            }
        }
    }
    __syncthreads();

    {
        #pragma unroll
        for (int nt = 4; nt < 8; nt++) {
            int col = w * 128 + nt * 16 + ln;
            const short* bb = fc2T + (w * 8 + nt) * 8 * 512 + laneoff;
            v4f acc0 = {0.f, 0.f, 0.f, 0.f}, acc1 = {0.f, 0.f, 0.f, 0.f}, acc2 = {0.f, 0.f, 0.f, 0.f};
            #pragma unroll
            for (int k0 = 0; k0 < 8; k0++) {
                v8s b  = *(const v8s*)(bb + k0 * 512);
                v8s a0 = *(const v8s*)&sX[(ln) * 264 + k0 * 32 + q * 8];
                v8s a1 = *(const v8s*)&sX[(16 + ln) * 264 + k0 * 32 + q * 8];
                v8s a2 = *(const v8s*)&sX[(32 + ln) * 264 + k0 * 32 + q * 8];
                acc0 = __builtin_amdgcn_mfma_f32_16x16x32_bf16(a0, b, acc0, 0, 0, 0);
                acc1 = __builtin_amdgcn_mfma_f32_16x16x32_bf16(a1, b, acc1, 0, 0, 0);
                acc2 = __builtin_amdgcn_mfma_f32_16x16x32_bf16(a2, b, acc2, 0, 0, 0);
            }
            float bias = ldf(fc2_b, col, bf);
            int wc = 12672 + w * 64 + (nt - 4) * 16 + ln;
            #pragma unroll
            for (int r = 0; r < 4; r++) {
                sHB[(q * 4 + r) * 264 + wc]      = f2s(lrelu(acc0[r] + bias));
                sHB[(16 + q * 4 + r) * 264 + wc] = f2s(lrelu(acc1[r] + bias));
                sHB[(32 + q * 4 + r) * 264 + wc] = f2s(lrelu(acc2[r] + bias));
            }
        }

        v4f accL[4][3];
        #pragma unroll
        for (int nt = 0; nt < 4; nt++)
            #pragma unroll
            for (int m = 0; m < 3; m++)
                accL[nt][m] = (v4f){0.f, 0.f, 0.f, 0.f};

        #pragma unroll
        for (int nt = 0; nt < 4; nt++) {
            const short* bb = fc2T + (w * 8 + nt) * 8 * 512 + laneoff;
            #pragma unroll
            for (int k0 = 0; k0 < 8; k0++) {
                v8s b  = *(const v8s*)(bb + k0 * 512);
                v8s a0 = *(const v8s*)&sX[(ln) * 264 + k0 * 32 + q * 8];
                v8s a1 = *(const v8s*)&sX[(16 + ln) * 264 + k0 * 32 + q * 8];
                v8s a2 = *(const v8s*)&sX[(32 + ln) * 264 + k0 * 32 + q * 8];
                accL[nt][0] = __builtin_amdgcn_mfma_f32_16x16x32_bf16(a0, b, accL[nt][0], 0, 0, 0);
                accL[nt][1] = __builtin_amdgcn_mfma_f32_16x16x32_bf16(a1, b, accL[nt][1], 0, 0, 0);
                accL[nt][2] = __builtin_amdgcn_mfma_f32_16x16x32_bf16(a2, b, accL[nt][2], 0, 0, 0);
            }
        }
        __syncthreads();   // all waves done READING sX; L bank region is dead

        #pragma unroll
        for (int nt = 0; nt < 4; nt++) {
            int col = w * 128 + nt * 16 + ln;
            float bias = ldf(fc2_b, col, bf);
            int wc = w * 64 + nt * 16 + ln;
            #pragma unroll
            for (int r = 0; r < 4; r++) {
                sHB[(q * 4 + r) * 264 + wc]      = f2s(lrelu(accL[nt][0][r] + bias));
                sHB[(16 + q * 4 + r) * 264 + wc] = f2s(lrelu(accL[nt][1][r] + bias));
                sHB[(32 + q * 4 + r) * 264 + wc] = f2s(lrelu(accL[nt][2][r] + bias));
            }
        }
    }
    __syncthreads();

    {
        v4f acc[4][3];
        #pragma unroll
        for (int nt = 0; nt < 4; nt++)
            #pragma unroll
            for (int m = 0; m < 3; m++)
                acc[nt][m] = (v4f){0.f, 0.f, 0.f, 0.f};

        #pragma unroll
        for (int half = 0; half < 2; half++) {
            v8s A0[8], A1[8], A2[8];
            #pragma unroll
            for (int k0 = 0; k0 < 8; k0++) {
                int c = half * 256 + k0 * 32 + q * 8;
                A0[k0] = *(const v8s*)&sHB[haddr(ln, c)];
                A1[k0] = *(const v8s*)&sHB[haddr(16 + ln, c)];
                A2[k0] = *(const v8s*)&sHB[haddr(32 + ln, c)];
            }
            #pragma unroll
            for (int nt = 0; nt < 4; nt++) {
                const short* bb = fc3T + ((w * 4 + nt) * 16 + half * 8) * 512 + laneoff;
                v8s B[8];
                #pragma unroll
                for (int k0 = 0; k0 < 8; k0++) B[k0] = *(const v8s*)(bb + k0 * 512);
                #pragma unroll
                for (int k0 = 0; k0 < 8; k0++) {
                    acc[nt][0] = __builtin_amdgcn_mfma_f32_16x16x32_bf16(A0[k0], B[k0], acc[nt][0], 0, 0, 0);
                    acc[nt][1] = __builtin_amdgcn_mfma_f32_16x16x32_bf16(A1[k0], B[k0], acc[nt][1], 0, 0, 0);
                    acc[nt][2] = __builtin_amdgcn_mfma_f32_16x16x32_bf16(A2[k0], B[k0], acc[nt][2], 0, 0, 0);
                }
            }
        }
        __syncthreads();   // all waves done READING H; safe to overwrite with s3

        #pragma unroll
        for (int nt = 0; nt < 4; nt++) {
            int col = w * 64 + nt * 16 + ln;
            float bias = ldf(fc3_b, col, bf);
            #pragma unroll
            for (int r = 0; r < 4; r++) {
                s3[(q * 4 + r) * 264 + col]      = f2s(lrelu(acc[nt][0][r] + bias));
                s3[(16 + q * 4 + r) * 264 + col] = f2s(lrelu(acc[nt][1][r] + bias));
                s3[(32 + q * 4 + r) * 264 + col] = f2s(lrelu(acc[nt][2][r] + bias));
            }
        }
    }
    __syncthreads();

    {
        int vi = t >> 2, l = t & 3;
        if (vi < MTV) {
            float p0 = 0.f, p1 = 0.f, p2 = 0.f;
            for (int k = l * 8; k < 256; k += 32) {
                #pragma unroll
                for (int j = 0; j < 8; j++) {
                    float a = s2f(s3[vi * 264 + k + j]);
                    p0 += a * s2f(sW4[0 * 256 + k + j]);
                    p1 += a * s2f(sW4[1 * 256 + k + j]);
                    p2 += a * s2f(sW4[2 * 256 + k + j]);
                }
            }
            #pragma unroll
            for (int s = 2; s; s >>= 1) {
                p0 += __shfl_down(p0, s, 4);
                p1 += __shfl_down(p1, s, 4);
                p2 += __shfl_down(p2, s, 4);
            }
            if (l == 0) {
                int slot = base + vi;
                int vert = perm ? perm[slot] : slot;
                float vx, vy, vz;
                if (vperm) {
                    vx = vperm[slot * 3 + 0];
                    vy = vperm[slot * 3 + 1];
                    vz = vperm[slot * 3 + 2];
                } else {
                    vx = ldf(v, slot * 3 + 0, bf);
                    vy = ldf(v, slot * 3 + 1, bf);
                    vz = ldf(v, slot * 3 + 2, bf);
                }
                float o0 = vx + 0.1f * tanhf(p0 + ldf(fc4_b, 0, bf));
                float o1 = vy + 0.1f * tanhf(p1 + ldf(fc4_b, 1, bf));
                float o2 = vz + 0.1f * tanhf(p2 + ldf(fc4_b, 2, bf));
                if (bf) {
                    short* ob = (short*)out;
                    ob[vert * 3 + 0] = f2s(o0);
                    ob[vert * 3 + 1] = f2s(o1);
                    ob[vert * 3 + 2] = f2s(o2);
                } else {
                    float* of = (float*)out;
                    of[vert * 3 + 0] = o0;
                    of[vert * 3 + 1] = o1;
                    of[vert * 3 + 2] = o2;
                }
            }
        }
    }
}

// ================= SMALL-WS FALLBACK: R10 monolith =================
__global__ __launch_bounds__(256, 3) void fused_mfma_kernel(
    const void* __restrict__ v,
    const float* __restrict__ n_accum,
    const void* __restrict__ volume,
    const short* __restrict__ vol1,
    const short* __restrict__ vol2,
    const short* __restrict__ Wcomb,
    const float* __restrict__ bcomb,
    const short* __restrict__ fc2T,
    const short* __restrict__ fc3T,
    const void* __restrict__ fc1_w, const void* __restrict__ fc1_b,
    const void* __restrict__ fc2_b, const void* __restrict__ fc3_b,
    const void* __restrict__ fc4_w, const void* __restrict__ fc4_b,
    void* __restrict__ out,
    const int* __restrict__ flag)
{
    __shared__ __align__(16) char smem[51712];
    short* sX    = (short*)smem;
    short* sCube = (short*)(smem + 16896);
    short* sH    = (short*)(smem + 16896);
    short* s3    = (short*)smem;
    short* sW4   = (short*)(smem + 50176);

    const int bf = *flag;
    const int t = threadIdx.x;
    const int base = blockIdx.x * TVB;
    const int w = t >> 6, L = t & 63, q = L >> 4, ln = L & 15;
    const int laneoff = (q * 16 + ln) * 8;

    for (int idx = t; idx < TVB * 75; idx += 256) {
        int vl  = idx / 75;
        int r75 = idx - vl * 75;
        int n   = r75 / 25;
        int dd  = r75 - n * 25;
        int di  = dd / 5, dj = dd - di * 5;
        int vert = base + vl;
        short* dst = &sCube[vl * 392 + n * 125 + dd * 5];
        if (vert < NVERT) {
            float vx = ldf(v, vert * 3 + 0, bf);
            float vy = ldf(v, vert * 3 + 1, bf);
            float vz = ldf(v, vert * 3 + 2, bf);
            float scl = (n == 0) ? 96.0f : (n == 1 ? 48.0f : 24.0f);
            int lim = (LVOL >> n) - 3;
            int cx = (int)rintf((vx + 1.0f) * scl);
            int cy = (int)rintf((vy + 1.0f) * scl);
            int cz = (int)rintf((vz + 1.0f) * scl);
            cx = min(max(cx, 2), lim) + di - 2;
            cy = min(max(cy, 2), lim) + dj - 2;
            cz = min(max(cz, 2), lim);
            if (n == 0) {
                int b0 = (cx * LVOL + cy) * LVOL + (cz - 2);
                if (bf) {
                    const short* vp = (const short*)volume;
                    #pragma unroll
                    for (int i = 0; i < 5; i++) dst[i] = vp[b0 + i];
                } else {
                    const float* vp = (const float*)volume;
                    #pragma unroll
                    for (int i = 0; i < 5; i++) dst[i] = f2s(vp[b0 + i]);
                }
            } else {
                const short* lvl = (n == 1) ? vol1 : vol2;
                int dim = (n == 1) ? 96 : 48;
                int b0 = (cx * dim + cy) * dim + (cz - 2);
                #pragma unroll
                for (int i = 0; i < 5; i++) dst[i] = lvl[b0 + i];
            }
        } else {
            #pragma unroll
            for (int i = 0; i < 5; i++) dst[i] = 0;
        }
    }
    for (int idx = t; idx < TVB * 9; idx += 256) {
        int vl = idx / 9, rr = idx - vl * 9;
        sCube[vl * 392 + 375 + rr] = 0;
    }
    for (int i = t; i < 768; i += 256) {
        int j = i >> 8, k = i & 255;
        sW4[i] = f2s(ldf(fc4_w, k * 3 + j, bf));
    }
    {
        int vi = t & 31, cb = (t >> 5) * 16;
        int vert = base + vi;
        float i0 = 0.f, i1 = 0.f, i2 = 0.f, i3 = 0.f, i4 = 0.f, i5 = 0.f;
        if (vert < NVERT) {
            i0 = ldf(v, vert * 3 + 0, bf);
            i1 = ldf(v, vert * 3 + 1, bf);
            i2 = ldf(v, vert * 3 + 2, bf);
            float nx = n_accum[vert * 3 + 0];
            float ny = n_accum[vert * 3 + 1];
            float nz = n_accum[vert * 3 + 2];
            float inv = 1.0f / fmaxf(sqrtf(nx * nx + ny * ny + nz * nz), 1e-12f);
            i3 = nx * inv; i4 = ny * inv; i5 = nz * inv;
        }
        #pragma unroll
        for (int i = 0; i < 16; i++) {
            int c = cb + i;
            float acc = ldf(fc1_b, c, bf)
                      + i0 * ldf(fc1_w, 0 * 128 + c, bf)
                      + i1 * ldf(fc1_w, 1 * 128 + c, bf)
                      + i2 * ldf(fc1_w, 2 * 128 + c, bf)
                      + i3 * ldf(fc1_w, 3 * 128 + c, bf)
                      + i4 * ldf(fc1_w, 4 * 128 + c, bf)
                      + i5 * ldf(fc1_w, 5 * 128 + c, bf);
            sX[vi * 264 + c] = f2s(lrelu(acc));
        }
    }
    __syncthreads();

    #pragma unroll
    for (int nt = 0; nt < 2; nt++) {
        int col = w * 32 + nt * 16 + ln;
        const short* wb = Wcomb + ((w * 2 + nt) * 12 * 64) * 8 + laneoff;
        v4f acc0 = {0.f, 0.f, 0.f, 0.f}, acc1 = {0.f, 0.f, 0.f, 0.f};
        #pragma unroll
        for (int k0 = 0; k0 < 12; k0++) {
            v8s b  = *(const v8s*)(wb + k0 * 512);
            v8s a0 = *(const v8s*)&sCube[ln * 392 + k0 * 32 + q * 8];
            v8s a1 = *(const v8s*)&sCube[(16 + ln) * 392 + k0 * 32 + q * 8];
            acc0 = __builtin_amdgcn_mfma_f32_16x16x32_bf16(a0, b, acc0, 0, 0, 0);
            acc1 = __builtin_amdgcn_mfma_f32_16x16x32_bf16(a1, b, acc1, 0, 0, 0);
        }
        float bias = bcomb[col];
        #pragma unroll
        for (int r = 0; r < 4; r++) {
            sX[(q * 4 + r) * 264 + 128 + col]      = f2s(acc0[r] + bias);
            sX[(16 + q * 4 + r) * 264 + 128 + col] = f2s(acc1[r] + bias);
        }
    }
    __syncthreads();

    {
        v8s a0[8], a1[8];
        #pragma unroll
        for (int k0 = 0; k0 < 8; k0++) {
            a0[k0] = *(const v8s*)&sX[ln * 264 + k0 * 32 + q * 8];
            a1[k0] = *(const v8s*)&sX[(16 + ln) * 264 + k0 * 32 + q * 8];
        }
        #pragma unroll
        for (int nt = 0; nt < 8; nt++) {
            int col = w * 128 + nt * 16 + ln;
            const short* bb = fc2T + (w * 8 + nt) * 8 * 512 + laneoff;
            v4f acc0 = {0.f, 0.f, 0.f, 0.f}, acc1 = {0.f, 0.f, 0.f, 0.f};
            #pragma unroll
            for (int k0 = 0; k0 < 8; k0++) {
                v8s b = *(const v8s*)(bb + k0 * 512);
                acc0 = __builtin_amdgcn_mfma_f32_16x16x32_bf16(a0[k0], b, acc0, 0, 0, 0);
                acc1 = __builtin_amdgcn_mfma_f32_16x16x32_bf16(a1[k0], b, acc1, 0, 0, 0);
            }
            float bias = ldf(fc2_b, col, bf);
            #pragma unroll
            for (int r = 0; r < 4; r++) {
                sH[(q * 4 + r) * 520 + col]      = f2s(lrelu(acc0[r] + bias));
                sH[(16 + q * 4 + r) * 520 + col] = f2s(lrelu(acc1[r] + bias));
            }
        }
    }
    __syncthreads();

    {
        #pragma unroll
        for (int nt = 0; nt < 4; nt++) {
            int col = w * 64 + nt * 16 + ln;
            v4f acc0 = {0.f, 0.f, 0.f, 0.f}, acc1 = {0.f, 0.f, 0.f, 0.f};
            #pragma unroll
            for (int half = 0; half < 2; half++) {
                const short* bb = fc3T + ((w * 4 + nt) * 16 + half * 8) * 512 + laneoff;
                #pragma unroll
                for (int k0 = 0; k0 < 8; k0++) {
                    v8s b  = *(const v8s*)(bb + k0 * 512);
                    v8s a0 = *(const v8s*)&sH[ln * 520 + half * 256 + k0 * 32 + q * 8];
                    v8s a1 = *(const v8s*)&sH[(16 + ln) * 520 + half * 256 + k0 * 32 + q * 8];
                    acc0 = __builtin_amdgcn_mfma_f32_16x16x32_bf16(a0, b, acc0, 0, 0, 0);
                    acc1 = __builtin_amdgcn_mfma_f32_16x16x32_bf16(a1, b, acc1, 0, 0, 0);
                }
            }
            float bias = ldf(fc3_b, col, bf);
            #pragma unroll
            for (int r = 0; r < 4; r++) {
                s3[(q * 4 + r) * 264 + col]      = f2s(lrelu(acc0[r] + bias));
                s3[(16 + q * 4 + r) * 264 + col] = f2s(lrelu(acc1[r] + bias));
            }
        }
    }
    __syncthreads();

    {
        int vi = t >> 3, l = t & 7;
        float p0 = 0.f, p1 = 0.f, p2 = 0.f;
        for (int k = l; k < 256; k += 8) {
            float a = s2f(s3[vi * 264 + k]);
            p0 += a * s2f(sW4[0 * 256 + k]);
            p1 += a * s2f(sW4[1 * 256 + k]);
            p2 += a * s2f(sW4[2 * 256 + k]);
        }
        #pragma unroll
        for (int s = 4; s; s >>= 1) {
            p0 += __shfl_down(p0, s, 8);
            p1 += __shfl_down(p1, s, 8);
            p2 += __shfl_down(p2, s, 8);
        }
        if (l == 0) {
            int vert = base + vi;
            if (vert < NVERT) {
                float vx = ldf(v, vert * 3 + 0, bf);
                float vy = ldf(v, vert * 3 + 1, bf);
                float vz = ldf(v, vert * 3 + 2, bf);
                float o0 = vx + 0.1f * tanhf(p0 + ldf(fc4_b, 0, bf));
                float o1 = vy + 0.1f * tanhf(p1 + ldf(fc4_b, 1, bf));
                float o2 = vz + 0.1f * tanhf(p2 + ldf(fc4_b, 2, bf));
                if (bf) {
                    short* ob = (short*)out;
                    ob[vert * 3 + 0] = f2s(o0);
                    ob[vert * 3 + 1] = f2s(o1);
                    ob[vert * 3 + 2] = f2s(o2);
                } else {
                    float* of = (float*)out;
                    of[vert * 3 + 0] = o0;
                    of[vert * 3 + 1] = o1;
                    of[vert * 3 + 2] = o2;
                }
            }
        }
    }
}

extern "C" void kernel_launch(void* const* d_in, const int* in_sizes, int n_in,
                              void* d_out, int out_size, void* d_ws, size_t ws_size,
                              hipStream_t stream) {
    const void* v      = d_in[0];
    const int*  f      = (const int*)d_in[1];
    const void* volume = d_in[2];
    const void* fc1_w  = d_in[3];
    const void* fc1_b  = d_in[4];
    const void* fc2_w  = d_in[5];
    const void* fc2_b  = d_in[6];
    const void* fc3_w  = d_in[7];
    const void* fc3_b  = d_in[8];
    const void* fc4_w  = d_in[9];
    const void* fc4_b  = d_in[10];
    const void* conv_w = d_in[11];
    const void* conv_b = d_in[12];
    const void* lfc_w  = d_in[13];
    const void* lfc_b  = d_in[14];

    char* wsb = (char*)d_ws;
    const int big  = (ws_size >= WS_BIG_NEED) ? 1 : 0;
    const int b16  = (ws_size >= WS_B16_NEED) ? 1 : 0;
    const int srt  = (ws_size >= WS_SORT_NEED) ? 1 : 0;

    if (big) {
        int*   flag    = (int*)wsb;
        float* n_accum = (float*)(wsb + 64);
        short* vol1b   = (short*)(wsb + 1800064);   // 96^3 bf16
        short* vol2b   = (short*)(wsb + 5339008);   // 48^3 bf16
        short* Wcomb8  = (short*)(wsb + 5560192);   // 128 x 608 bf16
        short* Wcomb   = (short*)(wsb + 5781376);   // 128 x 384 bf16 (legacy)
        float* bcomb   = (float*)(wsb + 5879680);
        short* fc2T    = (short*)(wsb + 5880192);
        short* fc3T    = (short*)(wsb + 6142336);
        short* xloc    = (short*)(wsb + 6404480);
        short* vol0b   = b16 ? (short*)(wsb + 44808576) : nullptr;
        int*   hist    = srt ? (int*)(wsb + 58964352) : nullptr;
        int*   keys    = srt ? (int*)(wsb + 59019648) : nullptr;
        int*   perm    = srt ? (int*)(wsb + 59619648) : nullptr;
        int*   rank    = srt ? (int*)(wsb + 60219648) : nullptr;
        float* vperm   = srt ? (float*)(wsb + 60819648) : nullptr;

        hipMemsetAsync(n_accum, 0, NVERT * 3 * sizeof(float), stream);
        detect_kernel<<<1, 256, 0, stream>>>(v, flag);
        if (srt) {
            hipMemsetAsync(hist, 0, NBUCKET * sizeof(int), stream);
            sort_hist_kernel<<<(NVERT + 255) / 256, 256, 0, stream>>>(v, hist, keys, flag);
            sort_scan_kernel<<<1, 1024, 0, stream>>>(hist);
            sort_scatter_kernel<<<(NVERT + 255) / 256, 256, 0, stream>>>(v, hist, keys, perm, rank, vperm, flag);
        }
        mega_prep2_kernel<<<P2_CP0_START + (b16 ? P2_CP0 : 0), 256, 0, stream>>>(
            volume, vol1b, vol2b,
            conv_w, lfc_w, conv_b, lfc_b, Wcomb, Wcomb8, bcomb, flag, vol0b);
        int ngather = (NVERT + TVB - 1) / TVB;
        if (srt) {
            gather8_kernel<<<ngather + NB_NORM + NB_TRS, 256, 0, stream>>>(
                v, f, n_accum, volume, vol1b, vol2b, vol0b, vperm, rank, Wcomb8, bcomb,
                fc2_w, fc3_w, fc2T, fc3T, xloc, flag, ngather);
        } else {
            gather_ext_kernel<<<ngather + NB_NORM + NB_TRS, 256, 0, stream>>>(
                v, f, n_accum, volume, vol1b, vol2b, vol0b, Wcomb, bcomb,
                fc2_w, fc3_w, fc2T, fc3T, xloc, flag, ngather);
        }
        mlp_kernel<<<(NVERT + MTV - 1) / MTV, 256, 0, stream>>>(
            v, vperm, n_accum, xloc, perm, fc2T, fc3T,
            fc1_w, fc1_b, fc2_b, fc3_b, fc4_w, fc4_b, d_out, flag);
    } else {
        int*   flag    = (int*)wsb;
        float* n_accum = (float*)(wsb + 64);
        short* vol1    = (short*)(wsb + 1800064);
        short* vol2    = (short*)(wsb + 3569536);
        short* Wcomb   = (short*)(wsb + 3790720);
        float* bcomb   = (float*)(wsb + 3889024);
        short* fc2T    = (short*)(wsb + 3889536);
        short* fc3T    = (short*)(wsb + 4151680);

        hipMemsetAsync(n_accum, 0, NVERT * 3 * sizeof(float), stream);
        detect_kernel<<<1, 256, 0, stream>>>(v, flag);
        mega_prep2_kernel<<<P2_WC8_START, 256, 0, stream>>>(
            volume, vol1, vol2,
            conv_w, lfc_w, conv_b, lfc_b, Wcomb, nullptr, bcomb, flag, nullptr);
        gather_ext_kernel<<<NB_NORM + NB_TRS, 256, 0, stream>>>(
            v, f, n_accum, volume, vol1, vol2, nullptr, Wcomb, bcomb,
            fc2_w, fc3_w, fc2T, fc3T, nullptr, flag, 0);
        fused_mfma_kernel<<<(NVERT + TVB - 1) / TVB, 256, 0, stream>>>(
            v, n_accum, volume, vol1, vol2, Wcomb, bcomb, fc2T, fc3T,
            fc1_w, fc1_b, fc2_b, fc3_b, fc4_w, fc4_b, d_out, flag);
    }
}